// Round 1
// baseline (1582.143 us; speedup 1.0000x reference)
//
#include <hip/hip_runtime.h>

#define TPB 256

static constexpr unsigned SPLITC   = 32508224u;   // out_size in floats; t3 scratch split point
static constexpr int      HWc      = 16384;       // 128*128
static constexpr float    NINV     = 1.0f / 1048576.0f; // 1/(B*H*W)

static constexpr unsigned FI_OFF    = 0u;
static constexpr unsigned WI_OFF    = 15728640u;
static constexpr unsigned VALS_OFF  = 15728960u;
static constexpr unsigned ORDER_OFF = 15729984u;
static constexpr unsigned CGH_OFF   = 15731008u;

__device__ __forceinline__ float wave_sum(float v) {
#pragma unroll
    for (int o = 1; o < 64; o <<= 1) v += __shfl_xor(v, o, 64);
    return v;
}

// ---------------- Pass 1: conv1 (1x1, 16->32) batch stats only ----------------
__global__ __launch_bounds__(TPB) void k_stats1(const float* __restrict__ x,
                                                const float* __restrict__ w1,
                                                float* __restrict__ bkt) {
    __shared__ __align__(16) float w1s[512];
    __shared__ float red[4][32][2];
    int tid = threadIdx.x;
    for (int e = tid; e < 512; e += TPB) w1s[e] = w1[e];
    __syncthreads();
    unsigned pid = blockIdx.x * TPB + tid;
    unsigned b = pid >> 14, p = pid & 16383u;
    const float* xp = x + (size_t)b * 16 * HWc + p;
    float xv[16];
#pragma unroll
    for (int c = 0; c < 16; ++c) xv[c] = xp[(size_t)c * HWc];
    int wv = tid >> 6;
    for (int co = 0; co < 32; ++co) {
        float a = 0.f;
#pragma unroll
        for (int c4 = 0; c4 < 4; ++c4) {
            float4 w = *(const float4*)&w1s[co * 16 + c4 * 4];
            a = fmaf(xv[c4 * 4 + 0], w.x, a); a = fmaf(xv[c4 * 4 + 1], w.y, a);
            a = fmaf(xv[c4 * 4 + 2], w.z, a); a = fmaf(xv[c4 * 4 + 3], w.w, a);
        }
        float s = wave_sum(a), q = wave_sum(a * a);
        if ((tid & 63) == 0) { red[wv][co][0] = s; red[wv][co][1] = q; }
    }
    __syncthreads();
    if (tid < 64) {
        int co = tid >> 1, st = tid & 1;
        float v = red[0][co][st] + red[1][co][st] + red[2][co][st] + red[3][co][st];
        atomicAdd(&bkt[(blockIdx.x & 63u) * 64u + (unsigned)tid], v);
    }
}

// ------------- stats finalize: buckets -> (scale, shift) per channel -------------
__global__ void k_sfin(const float* __restrict__ bkt, const float* __restrict__ g,
                       const float* __restrict__ bb, float* __restrict__ prm, int C) {
    int co = threadIdx.x;
    float s = 0.f, q = 0.f;
    for (int k = 0; k < 64; ++k) { s += bkt[(k * C + co) * 2]; q += bkt[(k * C + co) * 2 + 1]; }
    float mean = s * NINV;
    float var = q * NINV - mean * mean;
    float sc = g[co] * rsqrtf(var + 1e-5f);
    prm[co * 2] = sc;
    prm[co * 2 + 1] = bb[co] - mean * sc;
}

// -------- Pass 2: conv1+BN1+ReLU+conv2 (1x1, 32->64) -> t2 raw + stats2 --------
__global__ __launch_bounds__(TPB) void k_conv12(const float* __restrict__ x,
                                                const float* __restrict__ w1,
                                                const float* __restrict__ w2,
                                                const float* __restrict__ prm1,
                                                float* __restrict__ t2,
                                                float* __restrict__ bkt) {
    __shared__ __align__(16) float w1s[512];
    __shared__ __align__(16) float w2s[2048];
    __shared__ float p1[64];
    __shared__ float red[4][64][2];
    int tid = threadIdx.x;
    for (int e = tid; e < 512; e += TPB) w1s[e] = w1[e];
    for (int e = tid; e < 2048; e += TPB) w2s[e] = w2[e];
    if (tid < 64) p1[tid] = prm1[tid];
    __syncthreads();
    unsigned pid = blockIdx.x * TPB + tid;
    unsigned b = pid >> 14, p = pid & 16383u;
    const float* xp = x + (size_t)b * 16 * HWc + p;
    float xv[16];
#pragma unroll
    for (int c = 0; c < 16; ++c) xv[c] = xp[(size_t)c * HWc];
    float v1[32];
#pragma unroll
    for (int co = 0; co < 32; ++co) {
        float a = 0.f;
#pragma unroll
        for (int c4 = 0; c4 < 4; ++c4) {
            float4 w = *(const float4*)&w1s[co * 16 + c4 * 4];
            a = fmaf(xv[c4 * 4 + 0], w.x, a); a = fmaf(xv[c4 * 4 + 1], w.y, a);
            a = fmaf(xv[c4 * 4 + 2], w.z, a); a = fmaf(xv[c4 * 4 + 3], w.w, a);
        }
        v1[co] = fmaxf(0.f, fmaf(a, p1[co * 2], p1[co * 2 + 1]));
    }
    float* op = t2 + (size_t)b * 64 * HWc + p;
    int wv = tid >> 6;
    for (int co = 0; co < 64; ++co) {
        float a = 0.f;
#pragma unroll
        for (int c8 = 0; c8 < 8; ++c8) {
            float4 w = *(const float4*)&w2s[co * 32 + c8 * 4];
            a = fmaf(v1[c8 * 4 + 0], w.x, a); a = fmaf(v1[c8 * 4 + 1], w.y, a);
            a = fmaf(v1[c8 * 4 + 2], w.z, a); a = fmaf(v1[c8 * 4 + 3], w.w, a);
        }
        op[(size_t)co * HWc] = a;
        float s = wave_sum(a), q = wave_sum(a * a);
        if ((tid & 63) == 0) { red[wv][co][0] = s; red[wv][co][1] = q; }
    }
    __syncthreads();
    if (tid < 128) {
        int co = tid >> 1, st = tid & 1;
        float v = red[0][co][st] + red[1][co][st] + red[2][co][st] + red[3][co][st];
        atomicAdd(&bkt[(blockIdx.x & 63u) * 128u + (unsigned)tid], v);
    }
}

// ------ Pass 3/4: 3x3 conv (BN+ReLU fused on input load), CO=32, tiled ------
// block: 256 thr; tile 32x8 px; thread: 4 px (x-consecutive) x 8 co (by wave)
template <int CI>
__global__ __launch_bounds__(TPB) void k_conv3x3(const float* __restrict__ inA,
                                                 const float* __restrict__ inB,
                                                 const float* __restrict__ wc,
                                                 const float* __restrict__ prmIn,
                                                 float* __restrict__ outA,
                                                 float* __restrict__ outB,
                                                 float* __restrict__ bkt) {
    constexpr int CH = 8;
    __shared__ __align__(16) float xs[CH][10][35];
    __shared__ __align__(16) float wsd[CH][9][32];
    __shared__ float prm[CI * 2];
    __shared__ float red[4][8][2];
    int tid = threadIdx.x;
    for (int e = tid; e < CI * 2; e += TPB) prm[e] = prmIn[e];
    int tx = tid & 7, ty = (tid >> 3) & 7, coq = tid >> 6;
    int b = blockIdx.z;
    int x0 = blockIdx.x * 32, y0 = blockIdx.y * 8;
    unsigned bbase = (unsigned)b * CI * HWc;
    float acc[4][8];
#pragma unroll
    for (int p = 0; p < 4; ++p)
#pragma unroll
        for (int j = 0; j < 8; ++j) acc[p][j] = 0.f;

    for (int c0 = 0; c0 < CI; c0 += CH) {
        __syncthreads();
        // stage input tile (with halo), BN+ReLU applied
        for (int e = tid; e < CH * 340; e += TPB) {
            int ci = e / 340; int rem = e - ci * 340;
            int r = rem / 34;  int cc = rem - r * 34;
            int gy = y0 - 1 + r, gx = x0 - 1 + cc;
            float v = 0.f;
            if ((unsigned)gy < 128u && (unsigned)gx < 128u) {
                unsigned idx = bbase + (unsigned)(c0 + ci) * HWc + (unsigned)(gy * 128 + gx);
                float raw = (idx < SPLITC) ? inA[idx] : inB[idx - SPLITC];
                v = fmaxf(0.f, fmaf(raw, prm[(c0 + ci) * 2], prm[(c0 + ci) * 2 + 1]));
            }
            xs[ci][r][cc] = v;
        }
        // stage weights: wsd[ci][tap][co]
        for (int e = tid; e < CH * 288; e += TPB) {
            int co = e & 31; int t9 = (e >> 5) % 9; int ci = e / 288;
            wsd[ci][t9][co] = wc[(co * CI + c0 + ci) * 9 + t9];
        }
        __syncthreads();
        for (int ci = 0; ci < CH; ++ci) {
            float xl[3][6];
#pragma unroll
            for (int dy = 0; dy < 3; ++dy)
#pragma unroll
                for (int dx = 0; dx < 6; ++dx) xl[dy][dx] = xs[ci][ty + dy][tx * 4 + dx];
#pragma unroll
            for (int dy = 0; dy < 3; ++dy)
#pragma unroll
                for (int dx = 0; dx < 3; ++dx) {
                    const float4* wp = (const float4*)&wsd[ci][dy * 3 + dx][coq * 8];
                    float4 wa = wp[0], wb = wp[1];
#pragma unroll
                    for (int p = 0; p < 4; ++p) {
                        float xvv = xl[dy][p + dx];
                        acc[p][0] = fmaf(xvv, wa.x, acc[p][0]);
                        acc[p][1] = fmaf(xvv, wa.y, acc[p][1]);
                        acc[p][2] = fmaf(xvv, wa.z, acc[p][2]);
                        acc[p][3] = fmaf(xvv, wa.w, acc[p][3]);
                        acc[p][4] = fmaf(xvv, wb.x, acc[p][4]);
                        acc[p][5] = fmaf(xvv, wb.y, acc[p][5]);
                        acc[p][6] = fmaf(xvv, wb.z, acc[p][6]);
                        acc[p][7] = fmaf(xvv, wb.w, acc[p][7]);
                    }
                }
        }
    }
    unsigned obase = (unsigned)b * 32 * HWc;
    int gy = y0 + ty, gx = x0 + tx * 4;
#pragma unroll
    for (int j = 0; j < 8; ++j) {
        int co = coq * 8 + j;
        unsigned off = obase + (unsigned)co * HWc + (unsigned)(gy * 128 + gx);
        float4 v = make_float4(acc[0][j], acc[1][j], acc[2][j], acc[3][j]);
        if (off < SPLITC) *(float4*)(outA + off) = v;
        else              *(float4*)(outB + (off - SPLITC)) = v;
    }
#pragma unroll
    for (int j = 0; j < 8; ++j) {
        float s = acc[0][j] + acc[1][j] + acc[2][j] + acc[3][j];
        float q = acc[0][j] * acc[0][j] + acc[1][j] * acc[1][j] +
                  acc[2][j] * acc[2][j] + acc[3][j] * acc[3][j];
        s = wave_sum(s); q = wave_sum(q);
        if ((tid & 63) == 0) { red[coq][j][0] = s; red[coq][j][1] = q; }
    }
    __syncthreads();
    if (tid < 64) {
        int co = tid >> 1, st = tid & 1;
        float v = red[co >> 3][co & 7][st];
        unsigned blin = blockIdx.x + 4u * blockIdx.y + 64u * blockIdx.z;
        atomicAdd(&bkt[(blin & 63u) * 64u + (unsigned)tid], v);
    }
}

// ---- Pass 5: BN4+ReLU + fc1/tanh + fc2/tanh + per-batch token-sum of w0 ----
__global__ __launch_bounds__(TPB) void k_fc(const float* __restrict__ t4,
                                            const float* __restrict__ prm4,
                                            const float* __restrict__ fw1,
                                            const float* __restrict__ fb1,
                                            const float* __restrict__ fw2,
                                            const float* __restrict__ fb2,
                                            float* __restrict__ y0sum) {
    __shared__ __align__(16) float w1s[1024];
    __shared__ __align__(16) float w2s[512];
    __shared__ float b1s[32], b2s[16], p4[64];
    __shared__ float red[4][16];
    int tid = threadIdx.x;
    for (int e = tid; e < 1024; e += TPB) w1s[e] = fw1[e];
    for (int e = tid; e < 512; e += TPB) w2s[e] = fw2[e];
    if (tid < 32) b1s[tid] = fb1[tid];
    if (tid < 16) b2s[tid] = fb2[tid];
    if (tid < 64) p4[tid] = prm4[tid];
    __syncthreads();
    unsigned pid = blockIdx.x * TPB + tid;
    unsigned b = pid >> 14, p = pid & 16383u;
    const float* tp = t4 + (size_t)b * 32 * HWc + p;
    float v[32];
#pragma unroll
    for (int c = 0; c < 32; ++c) {
        float raw = tp[(size_t)c * HWc];
        v[c] = fmaxf(0.f, fmaf(raw, p4[c * 2], p4[c * 2 + 1]));
    }
    float h[32];
#pragma unroll
    for (int j = 0; j < 32; ++j) {
        float a = b1s[j];
#pragma unroll
        for (int c8 = 0; c8 < 8; ++c8) {
            float4 w = *(const float4*)&w1s[j * 32 + c8 * 4];
            a = fmaf(v[c8 * 4 + 0], w.x, a); a = fmaf(v[c8 * 4 + 1], w.y, a);
            a = fmaf(v[c8 * 4 + 2], w.z, a); a = fmaf(v[c8 * 4 + 3], w.w, a);
        }
        h[j] = tanhf(a);
    }
    int wv = tid >> 6;
    for (int k = 0; k < 16; ++k) {
        float a = b2s[k];
#pragma unroll
        for (int c8 = 0; c8 < 8; ++c8) {
            float4 w = *(const float4*)&w2s[k * 32 + c8 * 4];
            a = fmaf(h[c8 * 4 + 0], w.x, a); a = fmaf(h[c8 * 4 + 1], w.y, a);
            a = fmaf(h[c8 * 4 + 2], w.z, a); a = fmaf(h[c8 * 4 + 3], w.w, a);
        }
        a = tanhf(a);
        float s = wave_sum(a);
        if ((tid & 63) == 0) red[wv][k] = s;
    }
    __syncthreads();
    if (tid < 16) {
        float s = red[0][tid] + red[1][tid] + red[2][tid] + red[3][tid];
        atomicAdd(&y0sum[b * 16u + tid], s);
    }
}

// -------- Pass 6: finalize y0 -> wn, stable argsort, vals/order/wi, Cm, idx --------
__global__ void k_final(const float* __restrict__ y0sum, float* __restrict__ out,
                        float* __restrict__ Cm, int* __restrict__ idxb) {
    int b = threadIdx.x; // 64 threads
    float y0[16]; float nrm = 0.f;
#pragma unroll
    for (int i = 0; i < 16; ++i) { y0[i] = y0sum[b * 16 + i] * (1.0f / 16384.0f); nrm += y0[i] * y0[i]; }
    nrm = sqrtf(nrm);
    float wn[16]; int id[16];
#pragma unroll
    for (int i = 0; i < 16; ++i) { wn[i] = fabsf(y0[i]) * nrm; id[i] = i; }
    // stable insertion sort, descending (matches stable argsort of -wn)
    for (int i = 1; i < 16; ++i) {
        float k = wn[i]; int ii = id[i]; int j = i - 1;
        while (j >= 0 && wn[j] < k) { wn[j + 1] = wn[j]; id[j + 1] = id[j]; --j; }
        wn[j + 1] = k; id[j + 1] = ii;
    }
    for (int i = 0; i < 16; ++i) {
        out[VALS_OFF + b * 16 + i] = wn[i];
        out[ORDER_OFF + b * 16 + i] = (float)id[i];
    }
    for (int g = 0; g < 5; ++g)
        out[WI_OFF + g * 64 + b] = (wn[g * 3] + wn[g * 3 + 1] + wn[g * 3 + 2]) * (1.0f / 3.0f);
    for (int i = 0; i < 16; ++i)
        for (int j = 0; j < 16; ++j) Cm[b * 256 + i * 16 + j] = y0[i] * y0[j];
    for (int s = 0; s < 15; ++s) idxb[b * 15 + s] = id[s];
}

// -------- Pass 7: read x once -> cgh (Cm @ x) and fi (channel gather) --------
__global__ __launch_bounds__(TPB) void k_out(const float* __restrict__ x,
                                             const float* __restrict__ Cm,
                                             const int* __restrict__ idxb,
                                             float* __restrict__ out) {
    __shared__ float cm[256];
    __shared__ int idl[15];
    int tid = threadIdx.x;
    unsigned b = blockIdx.x >> 6;
    unsigned p = ((blockIdx.x & 63u) << 8) + tid;
    cm[tid] = Cm[b * 256u + tid];
    if (tid < 15) idl[tid] = idxb[b * 15u + tid];
    __syncthreads();
    const float* xp = x + (size_t)b * 16 * HWc + p;
    float xv[16];
#pragma unroll
    for (int j = 0; j < 16; ++j) xv[j] = xp[(size_t)j * HWc];
    float* og = out + CGH_OFF + (size_t)b * 16 * HWc + p;
    for (int i = 0; i < 16; ++i) {
        float a = 0.f;
#pragma unroll
        for (int j = 0; j < 16; ++j) a = fmaf(cm[i * 16 + j], xv[j], a);
        og[(size_t)i * HWc] = a;
    }
#pragma unroll
    for (int s = 0; s < 15; ++s) {
        int ch = idl[s];
        float vv = xp[(size_t)ch * HWc];
        int g = s / 3, r = s - 3 * g;
        out[(size_t)((g * 64 + (int)b) * 3 + r) * HWc + p] = vv;
    }
}

extern "C" void kernel_launch(void* const* d_in, const int* in_sizes, int n_in,
                              void* d_out, int out_size, void* d_ws, size_t ws_size,
                              hipStream_t stream) {
    const float* x    = (const float*)d_in[0];
    const float* w1   = (const float*)d_in[1];
    const float* bn1g = (const float*)d_in[2];  const float* bn1b = (const float*)d_in[3];
    const float* w2   = (const float*)d_in[4];
    const float* bn2g = (const float*)d_in[5];  const float* bn2b = (const float*)d_in[6];
    const float* w3   = (const float*)d_in[7];
    const float* bn3g = (const float*)d_in[8];  const float* bn3b = (const float*)d_in[9];
    const float* w4   = (const float*)d_in[10];
    const float* bn4g = (const float*)d_in[11]; const float* bn4b = (const float*)d_in[12];
    const float* fw1  = (const float*)d_in[13]; const float* fb1  = (const float*)d_in[14];
    const float* fw2  = (const float*)d_in[15]; const float* fb2  = (const float*)d_in[16];
    float* out = (float*)d_out;
    float* wsf = (float*)d_ws;

    // ws layout (floats):
    //   t2  @ 0            : 67,108,864 (256 MB)  [conv2 raw]
    //   t4  @ 0            : 33,554,432 (aliases t2; t2 dead after conv3)
    //   acc @ 67,108,864   : buckets/params/Cm/idx/spill
    float* t2  = wsf;
    float* t4  = wsf;
    float* acc = wsf + 67108864;
    float* b1 = acc;          float* b2 = acc + 4096;
    float* b3 = acc + 12288;  float* b4 = acc + 16384;
    float* y0s = acc + 20480;
    float* pr1 = acc + 21504; float* pr2 = acc + 21568;
    float* pr3 = acc + 21696; float* pr4 = acc + 21760;
    float* Cm  = acc + 21824;
    int*   idxb = (int*)(acc + 38208);
    float* spill = acc + 39168;                 // 1,046,208 floats (t3 overflow)
    size_t need = (size_t)(67108864 + 39168 + 1046208) * 4;
    if (ws_size < need) return;                 // fail loudly rather than corrupt

    // t3 (conv3 raw, 33,554,432 floats) lives in d_out (overwritten later) + ws spill
    float* t3a = out;
    float* t3b = spill;

    hipMemsetAsync(acc, 0, 21504 * 4, stream);  // zero all accumulators every launch

    k_stats1<<<4096, TPB, 0, stream>>>(x, w1, b1);
    k_sfin<<<1, 32, 0, stream>>>(b1, bn1g, bn1b, pr1, 32);
    k_conv12<<<4096, TPB, 0, stream>>>(x, w1, w2, pr1, t2, b2);
    k_sfin<<<1, 64, 0, stream>>>(b2, bn2g, bn2b, pr2, 64);
    k_conv3x3<64><<<dim3(4, 16, 64), TPB, 0, stream>>>(t2, t2 + SPLITC, w3, pr2, t3a, t3b, b3);
    k_sfin<<<1, 32, 0, stream>>>(b3, bn3g, bn3b, pr3, 32);
    k_conv3x3<32><<<dim3(4, 16, 64), TPB, 0, stream>>>(t3a, t3b, w4, pr3, t4, t4 + SPLITC, b4);
    k_sfin<<<1, 32, 0, stream>>>(b4, bn4g, bn4b, pr4, 32);
    k_fc<<<4096, TPB, 0, stream>>>(t4, pr4, fw1, fb1, fw2, fb2, y0s);
    k_final<<<1, 64, 0, stream>>>(y0s, out, Cm, idxb);
    k_out<<<4096, TPB, 0, stream>>>(x, Cm, idxb, out);
}

// Round 2
// 1266.834 us; speedup vs baseline: 1.2489x; 1.2489x over previous
//
#include <hip/hip_runtime.h>

#define TPB 256

static constexpr unsigned SPLITC = 32508224u;   // out_size in floats/uints; raw-t3 split point
static constexpr int      HWc    = 16384;       // 128*128
static constexpr float    NINV   = 1.0f / 1048576.0f; // 1/(B*H*W)

static constexpr unsigned FI_OFF    = 0u;
static constexpr unsigned WI_OFF    = 15728640u;
static constexpr unsigned VALS_OFF  = 15728960u;
static constexpr unsigned ORDER_OFF = 15729984u;
static constexpr unsigned CGH_OFF   = 15731008u;

typedef _Float16 f16;
typedef f16   f16x8 __attribute__((ext_vector_type(8)));
typedef f16   f16x4 __attribute__((ext_vector_type(4)));
typedef float f32x4 __attribute__((ext_vector_type(4)));

__device__ __forceinline__ float wave_sum(float v) {
#pragma unroll
    for (int o = 1; o < 64; o <<= 1) v += __shfl_xor(v, o, 64);
    return v;
}

// ---------------- Pass 1: conv1 (1x1, 16->32) batch stats only ----------------
__global__ __launch_bounds__(TPB) void k_stats1(const float* __restrict__ x,
                                                const float* __restrict__ w1,
                                                float* __restrict__ bkt) {
    __shared__ __align__(16) float w1s[512];
    __shared__ float red[4][32][2];
    int tid = threadIdx.x;
    for (int e = tid; e < 512; e += TPB) w1s[e] = w1[e];
    __syncthreads();
    unsigned pid = blockIdx.x * TPB + tid;
    unsigned b = pid >> 14, p = pid & 16383u;
    const float* xp = x + (size_t)b * 16 * HWc + p;
    float xv[16];
#pragma unroll
    for (int c = 0; c < 16; ++c) xv[c] = xp[(size_t)c * HWc];
    int wv = tid >> 6;
    for (int co = 0; co < 32; ++co) {
        float a = 0.f;
#pragma unroll
        for (int c4 = 0; c4 < 4; ++c4) {
            float4 w = *(const float4*)&w1s[co * 16 + c4 * 4];
            a = fmaf(xv[c4 * 4 + 0], w.x, a); a = fmaf(xv[c4 * 4 + 1], w.y, a);
            a = fmaf(xv[c4 * 4 + 2], w.z, a); a = fmaf(xv[c4 * 4 + 3], w.w, a);
        }
        float s = wave_sum(a), q = wave_sum(a * a);
        if ((tid & 63) == 0) { red[wv][co][0] = s; red[wv][co][1] = q; }
    }
    __syncthreads();
    if (tid < 64) {
        int co = tid >> 1, st = tid & 1;
        float v = red[0][co][st] + red[1][co][st] + red[2][co][st] + red[3][co][st];
        atomicAdd(&bkt[(blockIdx.x & 63u) * 64u + (unsigned)tid], v);
    }
}

// ------------- stats finalize: buckets -> (scale, shift) per channel -------------
__global__ void k_sfin(const float* __restrict__ bkt, const float* __restrict__ g,
                       const float* __restrict__ bb, float* __restrict__ prm, int C) {
    int co = threadIdx.x;
    float s = 0.f, q = 0.f;
    for (int k = 0; k < 64; ++k) { s += bkt[(k * C + co) * 2]; q += bkt[(k * C + co) * 2 + 1]; }
    float mean = s * NINV;
    float var = q * NINV - mean * mean;
    float sc = g[co] * rsqrtf(var + 1e-5f);
    prm[co * 2] = sc;
    prm[co * 2 + 1] = bb[co] - mean * sc;
}

// -------- Pass 2a: conv1+BN1+ReLU+conv2 raw -> stats2 only (no store) --------
__global__ __launch_bounds__(TPB) void k_conv12a(const float* __restrict__ x,
                                                 const float* __restrict__ w1,
                                                 const float* __restrict__ w2,
                                                 const float* __restrict__ prm1,
                                                 float* __restrict__ bkt) {
    __shared__ __align__(16) float w1s[512];
    __shared__ __align__(16) float w2s[2048];
    __shared__ float p1[64];
    __shared__ float red[4][64][2];
    int tid = threadIdx.x;
    for (int e = tid; e < 512; e += TPB) w1s[e] = w1[e];
    for (int e = tid; e < 2048; e += TPB) w2s[e] = w2[e];
    if (tid < 64) p1[tid] = prm1[tid];
    __syncthreads();
    unsigned pid = blockIdx.x * TPB + tid;
    unsigned b = pid >> 14, p = pid & 16383u;
    const float* xp = x + (size_t)b * 16 * HWc + p;
    float xv[16];
#pragma unroll
    for (int c = 0; c < 16; ++c) xv[c] = xp[(size_t)c * HWc];
    float v1[32];
#pragma unroll
    for (int co = 0; co < 32; ++co) {
        float a = 0.f;
#pragma unroll
        for (int c4 = 0; c4 < 4; ++c4) {
            float4 w = *(const float4*)&w1s[co * 16 + c4 * 4];
            a = fmaf(xv[c4 * 4 + 0], w.x, a); a = fmaf(xv[c4 * 4 + 1], w.y, a);
            a = fmaf(xv[c4 * 4 + 2], w.z, a); a = fmaf(xv[c4 * 4 + 3], w.w, a);
        }
        v1[co] = fmaxf(0.f, fmaf(a, p1[co * 2], p1[co * 2 + 1]));
    }
    int wv = tid >> 6;
    for (int co = 0; co < 64; ++co) {
        float a = 0.f;
#pragma unroll
        for (int c8 = 0; c8 < 8; ++c8) {
            float4 w = *(const float4*)&w2s[co * 32 + c8 * 4];
            a = fmaf(v1[c8 * 4 + 0], w.x, a); a = fmaf(v1[c8 * 4 + 1], w.y, a);
            a = fmaf(v1[c8 * 4 + 2], w.z, a); a = fmaf(v1[c8 * 4 + 3], w.w, a);
        }
        float s = wave_sum(a), q = wave_sum(a * a);
        if ((tid & 63) == 0) { red[wv][co][0] = s; red[wv][co][1] = q; }
    }
    __syncthreads();
    if (tid < 128) {
        int co = tid >> 1, st = tid & 1;
        float v = red[0][co][st] + red[1][co][st] + red[2][co][st] + red[3][co][st];
        atomicAdd(&bkt[(blockIdx.x & 63u) * 128u + (unsigned)tid], v);
    }
}

// -- Pass 2b: recompute conv1..conv2, apply BN2+ReLU, split fp16, write NHWC planes --
__global__ __launch_bounds__(TPB) void k_conv12b(const float* __restrict__ x,
                                                 const float* __restrict__ w1,
                                                 const float* __restrict__ w2,
                                                 const float* __restrict__ prm1,
                                                 const float* __restrict__ prm2,
                                                 f16* __restrict__ t2H,
                                                 f16* __restrict__ t2L) {
    __shared__ __align__(16) float w1s[512];
    __shared__ __align__(16) float w2s[2048];
    __shared__ float p1[64];
    __shared__ float p2[128];
    int tid = threadIdx.x;
    for (int e = tid; e < 512; e += TPB) w1s[e] = w1[e];
    for (int e = tid; e < 2048; e += TPB) w2s[e] = w2[e];
    if (tid < 64) p1[tid] = prm1[tid];
    if (tid < 128) p2[tid] = prm2[tid];
    __syncthreads();
    unsigned pid = blockIdx.x * TPB + tid;
    unsigned b = pid >> 14, p = pid & 16383u;
    const float* xp = x + (size_t)b * 16 * HWc + p;
    float xv[16];
#pragma unroll
    for (int c = 0; c < 16; ++c) xv[c] = xp[(size_t)c * HWc];
    float v1[32];
#pragma unroll
    for (int co = 0; co < 32; ++co) {
        float a = 0.f;
#pragma unroll
        for (int c4 = 0; c4 < 4; ++c4) {
            float4 w = *(const float4*)&w1s[co * 16 + c4 * 4];
            a = fmaf(xv[c4 * 4 + 0], w.x, a); a = fmaf(xv[c4 * 4 + 1], w.y, a);
            a = fmaf(xv[c4 * 4 + 2], w.z, a); a = fmaf(xv[c4 * 4 + 3], w.w, a);
        }
        v1[co] = fmaxf(0.f, fmaf(a, p1[co * 2], p1[co * 2 + 1]));
    }
    f16* oh = t2H + (size_t)pid * 64;
    f16* ol = t2L + (size_t)pid * 64;
#pragma unroll
    for (int c8 = 0; c8 < 8; ++c8) {
        f16x8 hv, lv;
#pragma unroll
        for (int j = 0; j < 8; ++j) {
            int co = c8 * 8 + j;
            float a = 0.f;
#pragma unroll
            for (int q4 = 0; q4 < 8; ++q4) {
                float4 w = *(const float4*)&w2s[co * 32 + q4 * 4];
                a = fmaf(v1[q4 * 4 + 0], w.x, a); a = fmaf(v1[q4 * 4 + 1], w.y, a);
                a = fmaf(v1[q4 * 4 + 2], w.z, a); a = fmaf(v1[q4 * 4 + 3], w.w, a);
            }
            float v = fmaxf(0.f, fmaf(a, p2[co * 2], p2[co * 2 + 1]));
            f16 hh = (f16)v;
            f16 ll = (f16)(v - (float)hh);
            hv[j] = hh; lv[j] = ll;
        }
        *(f16x8*)(oh + c8 * 8) = hv;
        *(f16x8*)(ol + c8 * 8) = lv;
    }
}

// ---- weight prep: OIHW fp32 -> fragment-lane-ordered fp16 hi/lo chunks ----
template <int CI>
__global__ void k_wprep(const float* __restrict__ w, float* __restrict__ wsg) {
    constexpr int KS = CI / 32;
    constexpr int NF = 9 * KS * 2;
    int t = blockIdx.x * 256 + threadIdx.x;
    if (t >= NF * 64) return;
    int lane = t & 63, fr = t >> 6;
    int cf = fr & 1;
    int ks = (KS == 2) ? ((fr >> 1) & 1) : 0;
    int tap = fr >> (KS == 2 ? 2 : 1);
    int g = lane >> 4, p = lane & 15;
    int co = cf * 16 + p;
    f16x8 hv, lv;
#pragma unroll
    for (int j = 0; j < 8; ++j) {
        int ci = ks * 32 + g * 8 + j;
        float v = w[(co * CI + ci) * 9 + tap];
        f16 hh = (f16)v;
        f16 ll = (f16)(v - (float)hh);
        hv[j] = hh; lv[j] = ll;
    }
    ((f16x8*)wsg)[fr * 64 + lane] = hv;
    ((f16x8*)wsg)[(NF + fr) * 64 + lane] = lv;
}

// ------ Pass 3/4: 3x3 conv via split-fp16 MFMA, A direct-from-global NHWC ------
// grid 2048 blocks x 512 thr (8 waves). wave w handles row y0+w, x-half h, 64 px x 32 co.
template <int CI, int OUTRAW>
__global__ __launch_bounds__(512, 4) void k_conv3(const f16* __restrict__ inH,
                                                  const f16* __restrict__ inL,
                                                  const float* __restrict__ wsg,
                                                  unsigned* __restrict__ outA,
                                                  unsigned* __restrict__ outB,
                                                  float* __restrict__ t4,
                                                  float* __restrict__ bkt) {
    constexpr int KS = CI / 32;
    constexpr int NF = 9 * KS * 2;
    __shared__ f16 wlds[NF * 2 * 512];
    __shared__ float red[8][64];
    int tid = threadIdx.x;
    {   // stage weights linearly (lane-order fragments, conflict-free reads later)
        const uint4* s = (const uint4*)wsg;
        uint4* d = (uint4*)wlds;
        for (int i = tid; i < NF * 128; i += 512) d[i] = s[i];
    }
    __syncthreads();

    unsigned o = blockIdx.x;
    unsigned xcd = o & 7u, q = o >> 3;
    unsigned kk = q & 31u, grp = q >> 5;
    unsigned b = (grp << 3) | xcd;          // batch (XCD-locality swizzle)
    unsigned rg = kk & 15u, h = kk >> 4;    // rowgroup, x-half

    int lane = tid & 63, w = tid >> 6;
    int p = lane & 15, g = lane >> 4;
    int y = (int)rg * 8 + w;
    int x0 = (int)h * 64;
    int laneE = p * CI + g * 8;

    f32x4 acc[4][2];
#pragma unroll
    for (int f = 0; f < 4; ++f)
#pragma unroll
        for (int cf = 0; cf < 2; ++cf) acc[f][cf] = (f32x4){0.f, 0.f, 0.f, 0.f};

    const f16x8* wv = (const f16x8*)wlds;
    const f16x8 kZ = {0, 0, 0, 0, 0, 0, 0, 0};

    for (int dyi = 0; dyi < 3; ++dyi) {
        int yy = y + dyi - 1;
        if ((unsigned)yy >= 128u) continue;
        int rowE = (int)((b * 128u + (unsigned)yy) * 128u);
        for (int dxi = 0; dxi < 3; ++dxi) {
            int xs0 = x0 + dxi - 1;
#pragma unroll
            for (int ks = 0; ks < KS; ++ks) {
                int fr = ((dyi * 3 + dxi) * KS + ks) * 2;
                f16x8 bh0 = wv[(fr + 0) * 64 + lane];
                f16x8 bh1 = wv[(fr + 1) * 64 + lane];
                f16x8 bl0 = wv[(NF + fr + 0) * 64 + lane];
                f16x8 bl1 = wv[(NF + fr + 1) * 64 + lane];
#pragma unroll
                for (int f = 0; f < 4; ++f) {
                    int e = (rowE + xs0 + f * 16) * CI + ks * 32 + laneE;
                    f16x8 ah = *(const f16x8*)(inH + e);
                    f16x8 al = *(const f16x8*)(inL + e);
                    if (dxi == 0 && f == 0 && h == 0u && p == 0) { ah = kZ; al = kZ; }
                    if (dxi == 2 && f == 3 && h == 1u && p == 15) { ah = kZ; al = kZ; }
                    acc[f][0] = __builtin_amdgcn_mfma_f32_16x16x32_f16(ah, bh0, acc[f][0], 0, 0, 0);
                    acc[f][0] = __builtin_amdgcn_mfma_f32_16x16x32_f16(al, bh0, acc[f][0], 0, 0, 0);
                    acc[f][0] = __builtin_amdgcn_mfma_f32_16x16x32_f16(ah, bl0, acc[f][0], 0, 0, 0);
                    acc[f][1] = __builtin_amdgcn_mfma_f32_16x16x32_f16(ah, bh1, acc[f][1], 0, 0, 0);
                    acc[f][1] = __builtin_amdgcn_mfma_f32_16x16x32_f16(al, bh1, acc[f][1], 0, 0, 0);
                    acc[f][1] = __builtin_amdgcn_mfma_f32_16x16x32_f16(ah, bl1, acc[f][1], 0, 0, 0);
                }
            }
        }
    }

    // ---- stats: per-co sum/sumsq of fp32 accs ----
    float s0 = 0.f, q0 = 0.f, s1 = 0.f, q1 = 0.f;
#pragma unroll
    for (int f = 0; f < 4; ++f)
#pragma unroll
        for (int r = 0; r < 4; ++r) {
            float a = acc[f][0][r]; s0 += a; q0 += a * a;
            float c = acc[f][1][r]; s1 += c; q1 += c * c;
        }
    s0 += __shfl_xor(s0, 16, 64); s0 += __shfl_xor(s0, 32, 64);
    q0 += __shfl_xor(q0, 16, 64); q0 += __shfl_xor(q0, 32, 64);
    s1 += __shfl_xor(s1, 16, 64); s1 += __shfl_xor(s1, 32, 64);
    q1 += __shfl_xor(q1, 16, 64); q1 += __shfl_xor(q1, 32, 64);
    if (lane < 16) {
        red[w][lane * 4 + 0] = s0; red[w][lane * 4 + 1] = q0;
        red[w][lane * 4 + 2] = s1; red[w][lane * 4 + 3] = q1;
    }

    // ---- outputs: C layout col=lane&15 (co), row=4*(lane>>4)+reg (px) ----
    unsigned pxbase = b * 16384u + (unsigned)y * 128u + (unsigned)x0;
#pragma unroll
    for (int f = 0; f < 4; ++f)
#pragma unroll
        for (int cf = 0; cf < 2; ++cf)
#pragma unroll
            for (int r = 0; r < 4; ++r) {
                float v = acc[f][cf][r];
                unsigned px = pxbase + (unsigned)(f * 16 + g * 4 + r);
                unsigned co = (unsigned)(cf * 16 + p);
                if (OUTRAW) {
                    f16 hh = (f16)v;
                    f16 ll = (f16)(v - (float)hh);
                    unsigned u = (unsigned)__builtin_bit_cast(unsigned short, hh) |
                                 ((unsigned)__builtin_bit_cast(unsigned short, ll) << 16);
                    unsigned e = px * 32u + co;
                    if (e < SPLITC) outA[e] = u; else outB[e - SPLITC] = u;
                } else {
                    t4[px * 32u + co] = v;
                }
            }

    __syncthreads();
    if (tid < 64) {
        float v = 0.f;
#pragma unroll
        for (int ww = 0; ww < 8; ++ww) v += red[ww][tid];
        int l2 = tid >> 2, t = tid & 3;
        int co = l2 + ((t >> 1) << 4);
        int st = t & 1;
        atomicAdd(&bkt[((o & 63u) * 32u + (unsigned)co) * 2u + (unsigned)st], v);
    }
}

// ---- BN3+ReLU transform: raw interleaved split -> fp16 hi/lo planes ----
__global__ __launch_bounds__(256) void k_bn3(const unsigned* __restrict__ rawA,
                                             const unsigned* __restrict__ rawB,
                                             const float* __restrict__ pr3,
                                             f16* __restrict__ outH,
                                             f16* __restrict__ outL) {
    __shared__ float prs[64];
    int tid = threadIdx.x;
    if (tid < 64) prs[tid] = pr3[tid];
    __syncthreads();
    unsigned e = (blockIdx.x * 256u + tid) * 4u;
    uint4 u = (e < SPLITC) ? *(const uint4*)(rawA + e) : *(const uint4*)(rawB + (e - SPLITC));
    unsigned uu[4] = {u.x, u.y, u.z, u.w};
    f16x4 hv, lv;
#pragma unroll
    for (int j = 0; j < 4; ++j) {
        unsigned co = (e + j) & 31u;
        float v = (float)__builtin_bit_cast(f16, (unsigned short)(uu[j] & 0xFFFFu)) +
                  (float)__builtin_bit_cast(f16, (unsigned short)(uu[j] >> 16));
        float bnv = fmaxf(0.f, fmaf(v, prs[co * 2], prs[co * 2 + 1]));
        f16 hh = (f16)bnv;
        hv[j] = hh;
        lv[j] = (f16)(bnv - (float)hh);
    }
    *(f16x4*)(outH + e) = hv;
    *(f16x4*)(outL + e) = lv;
}

// ---- Pass 5: BN4+ReLU + fc1/tanh + fc2/tanh + per-batch token-sum of w0 ----
__global__ __launch_bounds__(TPB) void k_fc(const float* __restrict__ t4,
                                            const float* __restrict__ prm4,
                                            const float* __restrict__ fw1,
                                            const float* __restrict__ fb1,
                                            const float* __restrict__ fw2,
                                            const float* __restrict__ fb2,
                                            float* __restrict__ y0sum) {
    __shared__ __align__(16) float w1s[1024];
    __shared__ __align__(16) float w2s[512];
    __shared__ float b1s[32], b2s[16], p4[64];
    __shared__ float red[4][16];
    int tid = threadIdx.x;
    for (int e = tid; e < 1024; e += TPB) w1s[e] = fw1[e];
    for (int e = tid; e < 512; e += TPB) w2s[e] = fw2[e];
    if (tid < 32) b1s[tid] = fb1[tid];
    if (tid < 16) b2s[tid] = fb2[tid];
    if (tid < 64) p4[tid] = prm4[tid];
    __syncthreads();
    unsigned pid = blockIdx.x * TPB + tid;
    const float* tp = t4 + (size_t)pid * 32;   // NHWC
    float v[32];
#pragma unroll
    for (int c4 = 0; c4 < 8; ++c4) {
        float4 raw = *(const float4*)(tp + c4 * 4);
        v[c4 * 4 + 0] = fmaxf(0.f, fmaf(raw.x, p4[(c4 * 4 + 0) * 2], p4[(c4 * 4 + 0) * 2 + 1]));
        v[c4 * 4 + 1] = fmaxf(0.f, fmaf(raw.y, p4[(c4 * 4 + 1) * 2], p4[(c4 * 4 + 1) * 2 + 1]));
        v[c4 * 4 + 2] = fmaxf(0.f, fmaf(raw.z, p4[(c4 * 4 + 2) * 2], p4[(c4 * 4 + 2) * 2 + 1]));
        v[c4 * 4 + 3] = fmaxf(0.f, fmaf(raw.w, p4[(c4 * 4 + 3) * 2], p4[(c4 * 4 + 3) * 2 + 1]));
    }
    float hh[32];
#pragma unroll
    for (int j = 0; j < 32; ++j) {
        float a = b1s[j];
#pragma unroll
        for (int c8 = 0; c8 < 8; ++c8) {
            float4 w = *(const float4*)&w1s[j * 32 + c8 * 4];
            a = fmaf(v[c8 * 4 + 0], w.x, a); a = fmaf(v[c8 * 4 + 1], w.y, a);
            a = fmaf(v[c8 * 4 + 2], w.z, a); a = fmaf(v[c8 * 4 + 3], w.w, a);
        }
        hh[j] = tanhf(a);
    }
    unsigned bb = pid >> 14;
    int wv = tid >> 6;
    for (int k = 0; k < 16; ++k) {
        float a = b2s[k];
#pragma unroll
        for (int c8 = 0; c8 < 8; ++c8) {
            float4 w = *(const float4*)&w2s[k * 32 + c8 * 4];
            a = fmaf(hh[c8 * 4 + 0], w.x, a); a = fmaf(hh[c8 * 4 + 1], w.y, a);
            a = fmaf(hh[c8 * 4 + 2], w.z, a); a = fmaf(hh[c8 * 4 + 3], w.w, a);
        }
        a = tanhf(a);
        float s = wave_sum(a);
        if ((tid & 63) == 0) red[wv][k] = s;
    }
    __syncthreads();
    if (tid < 16) {
        float s = red[0][tid] + red[1][tid] + red[2][tid] + red[3][tid];
        atomicAdd(&y0sum[bb * 16u + tid], s);
    }
}

// -------- Pass 6: finalize y0 -> wn, stable argsort, vals/order/wi, Cm, idx --------
__global__ void k_final(const float* __restrict__ y0sum, float* __restrict__ out,
                        float* __restrict__ Cm, int* __restrict__ idxb) {
    int b = threadIdx.x; // 64 threads
    float y0[16]; float nrm = 0.f;
#pragma unroll
    for (int i = 0; i < 16; ++i) { y0[i] = y0sum[b * 16 + i] * (1.0f / 16384.0f); nrm += y0[i] * y0[i]; }
    nrm = sqrtf(nrm);
    float wn[16]; int id[16];
#pragma unroll
    for (int i = 0; i < 16; ++i) { wn[i] = fabsf(y0[i]) * nrm; id[i] = i; }
    for (int i = 1; i < 16; ++i) {
        float k = wn[i]; int ii = id[i]; int j = i - 1;
        while (j >= 0 && wn[j] < k) { wn[j + 1] = wn[j]; id[j + 1] = id[j]; --j; }
        wn[j + 1] = k; id[j + 1] = ii;
    }
    for (int i = 0; i < 16; ++i) {
        out[VALS_OFF + b * 16 + i] = wn[i];
        out[ORDER_OFF + b * 16 + i] = (float)id[i];
    }
    for (int g = 0; g < 5; ++g)
        out[WI_OFF + g * 64 + b] = (wn[g * 3] + wn[g * 3 + 1] + wn[g * 3 + 2]) * (1.0f / 3.0f);
    for (int i = 0; i < 16; ++i)
        for (int j = 0; j < 16; ++j) Cm[b * 256 + i * 16 + j] = y0[i] * y0[j];
    for (int s = 0; s < 15; ++s) idxb[b * 15 + s] = id[s];
}

// -------- Pass 7: read x once -> cgh (Cm @ x) and fi (channel gather) --------
__global__ __launch_bounds__(TPB) void k_out(const float* __restrict__ x,
                                             const float* __restrict__ Cm,
                                             const int* __restrict__ idxb,
                                             float* __restrict__ out) {
    __shared__ float cm[256];
    __shared__ int idl[15];
    int tid = threadIdx.x;
    unsigned b = blockIdx.x >> 6;
    unsigned p = ((blockIdx.x & 63u) << 8) + tid;
    cm[tid] = Cm[b * 256u + tid];
    if (tid < 15) idl[tid] = idxb[b * 15u + tid];
    __syncthreads();
    const float* xp = x + (size_t)b * 16 * HWc + p;
    float xv[16];
#pragma unroll
    for (int j = 0; j < 16; ++j) xv[j] = xp[(size_t)j * HWc];
    float* og = out + CGH_OFF + (size_t)b * 16 * HWc + p;
    for (int i = 0; i < 16; ++i) {
        float a = 0.f;
#pragma unroll
        for (int j = 0; j < 16; ++j) a = fmaf(cm[i * 16 + j], xv[j], a);
        og[(size_t)i * HWc] = a;
    }
#pragma unroll
    for (int s = 0; s < 15; ++s) {
        int ch = idl[s];
        float vv = xp[(size_t)ch * HWc];
        int g = s / 3, r = s - 3 * g;
        out[(size_t)((g * 64 + (int)b) * 3 + r) * HWc + p] = vv;
    }
}

extern "C" void kernel_launch(void* const* d_in, const int* in_sizes, int n_in,
                              void* d_out, int out_size, void* d_ws, size_t ws_size,
                              hipStream_t stream) {
    const float* x    = (const float*)d_in[0];
    const float* w1   = (const float*)d_in[1];
    const float* bn1g = (const float*)d_in[2];  const float* bn1b = (const float*)d_in[3];
    const float* w2   = (const float*)d_in[4];
    const float* bn2g = (const float*)d_in[5];  const float* bn2b = (const float*)d_in[6];
    const float* w3   = (const float*)d_in[7];
    const float* bn3g = (const float*)d_in[8];  const float* bn3b = (const float*)d_in[9];
    const float* w4   = (const float*)d_in[10];
    const float* bn4g = (const float*)d_in[11]; const float* bn4b = (const float*)d_in[12];
    const float* fw1  = (const float*)d_in[13]; const float* fb1  = (const float*)d_in[14];
    const float* fw2  = (const float*)d_in[15]; const float* fb2  = (const float*)d_in[16];
    float* out = (float*)d_out;
    float* wsf = (float*)d_ws;

    // ws layout (floats):
    //   [0,1024)                      guard (negative-offset A loads land here)
    //   t2pH @ 1024        (33,554,432)  | after conv3: t3pH @1024 (16,777,216), t3pL follows
    //   t2pL @ 33,555,456  (33,554,432)  | after conv3: t4 @33,555,456 (33,554,432) NHWC fp32
    //   acc  @ 67,109,888  : buckets/params/Cm/idx/wsg/spill
    f16*   t2H  = (f16*)(wsf + 1024);
    f16*   t2L  = (f16*)(wsf + 33555456);
    f16*   t3H  = (f16*)(wsf + 1024);
    f16*   t3L  = (f16*)(wsf + 1024 + 16777216);
    float* t4   = wsf + 33555456;
    float* acc  = wsf + 67109888;
    float* b1   = acc;           float* b2  = acc + 4096;
    float* b3   = acc + 12288;   float* b4  = acc + 16384;
    float* y0s  = acc + 20480;
    float* pr1  = acc + 21504;   float* pr2 = acc + 21568;
    float* pr3  = acc + 21696;   float* pr4 = acc + 21760;
    float* Cm   = acc + 21824;
    int*   idxb = (int*)(acc + 38208);
    float* wsg3 = acc + 39168;                 // 18,432 floats (73,728 B)
    float* wsg4 = acc + 57600;                 // 9,216 floats
    unsigned* spillU = (unsigned*)(acc + 66816); // 1,046,208 uints (raw-t3 overflow)
    size_t need = (size_t)(67109888 + 66816 + 1046208) * 4;
    if (ws_size < need) return;

    unsigned* rawA = (unsigned*)out;           // raw conv3 split lives in d_out + spill

    hipMemsetAsync(acc, 0, 21504 * 4, stream);  // zero buckets + y0sum each launch

    k_wprep<64><<<9, 256, 0, stream>>>(w3, wsg3);
    k_wprep<32><<<5, 256, 0, stream>>>(w4, wsg4);
    k_stats1<<<4096, TPB, 0, stream>>>(x, w1, b1);
    k_sfin<<<1, 32, 0, stream>>>(b1, bn1g, bn1b, pr1, 32);
    k_conv12a<<<4096, TPB, 0, stream>>>(x, w1, w2, pr1, b2);
    k_sfin<<<1, 64, 0, stream>>>(b2, bn2g, bn2b, pr2, 64);
    k_conv12b<<<4096, TPB, 0, stream>>>(x, w1, w2, pr1, pr2, t2H, t2L);
    k_conv3<64, 1><<<2048, 512, 0, stream>>>(t2H, t2L, wsg3, rawA, spillU, nullptr, b3);
    k_sfin<<<1, 32, 0, stream>>>(b3, bn3g, bn3b, pr3, 32);
    k_bn3<<<32768, 256, 0, stream>>>(rawA, spillU, pr3, t3H, t3L);
    k_conv3<32, 0><<<2048, 512, 0, stream>>>(t3H, t3L, wsg4, nullptr, nullptr, t4, b4);
    k_sfin<<<1, 32, 0, stream>>>(b4, bn4g, bn4b, pr4, 32);
    k_fc<<<4096, TPB, 0, stream>>>(t4, pr4, fw1, fb1, fw2, fb2, y0s);
    k_final<<<1, 64, 0, stream>>>(y0s, out, Cm, idxb);
    k_out<<<4096, TPB, 0, stream>>>(x, Cm, idxb, out);
}

// Round 3
// 695.861 us; speedup vs baseline: 2.2736x; 1.8205x over previous
//
#include <hip/hip_runtime.h>

#define TPB 256

static constexpr int   HWc  = 16384;                 // 128*128
static constexpr float NINV = 1.0f / 1048576.0f;     // 1/(B*H*W)

static constexpr unsigned FI_OFF    = 0u;
static constexpr unsigned WI_OFF    = 15728640u;
static constexpr unsigned VALS_OFF  = 15728960u;
static constexpr unsigned ORDER_OFF = 15729984u;
static constexpr unsigned CGH_OFF   = 15731008u;

typedef _Float16 f16;
typedef f16   f16x8 __attribute__((ext_vector_type(8)));
typedef f16   f16x4 __attribute__((ext_vector_type(4)));
typedef float f32x4 __attribute__((ext_vector_type(4)));

__device__ __forceinline__ float wave_sum(float v) {
#pragma unroll
    for (int o = 1; o < 64; o <<= 1) v += __shfl_xor(v, o, 64);
    return v;
}

// async global->LDS, 16B per lane; LDS dest = wave base + lane*16 (linear layout)
__device__ __forceinline__ void gl_lds16(const void* g, void* l) {
    __builtin_amdgcn_global_load_lds(
        (const __attribute__((address_space(1))) unsigned int*)g,
        (__attribute__((address_space(3))) unsigned int*)l, 16, 0, 0);
}

// ---------------- Pass 1: conv1 (1x1, 16->32) batch stats only ----------------
__global__ __launch_bounds__(TPB) void k_stats1(const float* __restrict__ x,
                                                const float* __restrict__ w1,
                                                float* __restrict__ bkt) {
    __shared__ __align__(16) float w1s[512];
    __shared__ float red[4][32][2];
    int tid = threadIdx.x;
    for (int e = tid; e < 512; e += TPB) w1s[e] = w1[e];
    __syncthreads();
    unsigned pid = blockIdx.x * TPB + tid;
    unsigned b = pid >> 14, p = pid & 16383u;
    const float* xp = x + (size_t)b * 16 * HWc + p;
    float xv[16];
#pragma unroll
    for (int c = 0; c < 16; ++c) xv[c] = xp[(size_t)c * HWc];
    int wv = tid >> 6;
    for (int co = 0; co < 32; ++co) {
        float a = 0.f;
#pragma unroll
        for (int c4 = 0; c4 < 4; ++c4) {
            float4 w = *(const float4*)&w1s[co * 16 + c4 * 4];
            a = fmaf(xv[c4 * 4 + 0], w.x, a); a = fmaf(xv[c4 * 4 + 1], w.y, a);
            a = fmaf(xv[c4 * 4 + 2], w.z, a); a = fmaf(xv[c4 * 4 + 3], w.w, a);
        }
        float s = wave_sum(a), q = wave_sum(a * a);
        if ((tid & 63) == 0) { red[wv][co][0] = s; red[wv][co][1] = q; }
    }
    __syncthreads();
    if (tid < 64) {
        int co = tid >> 1, st = tid & 1;
        float v = red[0][co][st] + red[1][co][st] + red[2][co][st] + red[3][co][st];
        atomicAdd(&bkt[(blockIdx.x & 63u) * 64u + (unsigned)tid], v);
    }
}

// ------------- stats finalize: buckets -> (scale, shift) per channel -------------
__global__ void k_sfin(const float* __restrict__ bkt, const float* __restrict__ g,
                       const float* __restrict__ bb, float* __restrict__ prm, int C) {
    int co = threadIdx.x;
    float s = 0.f, q = 0.f;
    for (int k = 0; k < 64; ++k) { s += bkt[(k * C + co) * 2]; q += bkt[(k * C + co) * 2 + 1]; }
    float mean = s * NINV;
    float var = q * NINV - mean * mean;
    float sc = g[co] * rsqrtf(var + 1e-5f);
    prm[co * 2] = sc;
    prm[co * 2 + 1] = bb[co] - mean * sc;
}

// -------- Pass 2a: conv1+BN1+ReLU+conv2 raw -> stats2 only (no store) --------
__global__ __launch_bounds__(TPB) void k_conv12a(const float* __restrict__ x,
                                                 const float* __restrict__ w1,
                                                 const float* __restrict__ w2,
                                                 const float* __restrict__ prm1,
                                                 float* __restrict__ bkt) {
    __shared__ __align__(16) float w1s[512];
    __shared__ __align__(16) float w2s[2048];
    __shared__ float p1[64];
    __shared__ float red[4][64][2];
    int tid = threadIdx.x;
    for (int e = tid; e < 512; e += TPB) w1s[e] = w1[e];
    for (int e = tid; e < 2048; e += TPB) w2s[e] = w2[e];
    if (tid < 64) p1[tid] = prm1[tid];
    __syncthreads();
    unsigned pid = blockIdx.x * TPB + tid;
    unsigned b = pid >> 14, p = pid & 16383u;
    const float* xp = x + (size_t)b * 16 * HWc + p;
    float xv[16];
#pragma unroll
    for (int c = 0; c < 16; ++c) xv[c] = xp[(size_t)c * HWc];
    float v1[32];
#pragma unroll
    for (int co = 0; co < 32; ++co) {
        float a = 0.f;
#pragma unroll
        for (int c4 = 0; c4 < 4; ++c4) {
            float4 w = *(const float4*)&w1s[co * 16 + c4 * 4];
            a = fmaf(xv[c4 * 4 + 0], w.x, a); a = fmaf(xv[c4 * 4 + 1], w.y, a);
            a = fmaf(xv[c4 * 4 + 2], w.z, a); a = fmaf(xv[c4 * 4 + 3], w.w, a);
        }
        v1[co] = fmaxf(0.f, fmaf(a, p1[co * 2], p1[co * 2 + 1]));
    }
    int wv = tid >> 6;
    for (int co = 0; co < 64; ++co) {
        float a = 0.f;
#pragma unroll
        for (int c8 = 0; c8 < 8; ++c8) {
            float4 w = *(const float4*)&w2s[co * 32 + c8 * 4];
            a = fmaf(v1[c8 * 4 + 0], w.x, a); a = fmaf(v1[c8 * 4 + 1], w.y, a);
            a = fmaf(v1[c8 * 4 + 2], w.z, a); a = fmaf(v1[c8 * 4 + 3], w.w, a);
        }
        float s = wave_sum(a), q = wave_sum(a * a);
        if ((tid & 63) == 0) { red[wv][co][0] = s; red[wv][co][1] = q; }
    }
    __syncthreads();
    if (tid < 128) {
        int co = tid >> 1, st = tid & 1;
        float v = red[0][co][st] + red[1][co][st] + red[2][co][st] + red[3][co][st];
        atomicAdd(&bkt[(blockIdx.x & 63u) * 128u + (unsigned)tid], v);
    }
}

// -- Pass 2b: recompute conv1..conv2, BN2+ReLU, fp16, write two 32-ch NHWC planes --
__global__ __launch_bounds__(TPB) void k_conv12b(const float* __restrict__ x,
                                                 const float* __restrict__ w1,
                                                 const float* __restrict__ w2,
                                                 const float* __restrict__ prm1,
                                                 const float* __restrict__ prm2,
                                                 f16* __restrict__ t2a,
                                                 f16* __restrict__ t2b) {
    __shared__ __align__(16) float w1s[512];
    __shared__ __align__(16) float w2s[2048];
    __shared__ float p1[64];
    __shared__ float p2[128];
    int tid = threadIdx.x;
    for (int e = tid; e < 512; e += TPB) w1s[e] = w1[e];
    for (int e = tid; e < 2048; e += TPB) w2s[e] = w2[e];
    if (tid < 64) p1[tid] = prm1[tid];
    if (tid < 128) p2[tid] = prm2[tid];
    __syncthreads();
    unsigned pid = blockIdx.x * TPB + tid;
    unsigned b = pid >> 14, p = pid & 16383u;
    const float* xp = x + (size_t)b * 16 * HWc + p;
    float xv[16];
#pragma unroll
    for (int c = 0; c < 16; ++c) xv[c] = xp[(size_t)c * HWc];
    float v1[32];
#pragma unroll
    for (int co = 0; co < 32; ++co) {
        float a = 0.f;
#pragma unroll
        for (int c4 = 0; c4 < 4; ++c4) {
            float4 w = *(const float4*)&w1s[co * 16 + c4 * 4];
            a = fmaf(xv[c4 * 4 + 0], w.x, a); a = fmaf(xv[c4 * 4 + 1], w.y, a);
            a = fmaf(xv[c4 * 4 + 2], w.z, a); a = fmaf(xv[c4 * 4 + 3], w.w, a);
        }
        v1[co] = fmaxf(0.f, fmaf(a, p1[co * 2], p1[co * 2 + 1]));
    }
    f16* oa = t2a + (size_t)pid * 32;
    f16* ob = t2b + (size_t)pid * 32;
#pragma unroll
    for (int c8 = 0; c8 < 8; ++c8) {
        f16x8 hv;
#pragma unroll
        for (int j = 0; j < 8; ++j) {
            int co = c8 * 8 + j;
            float a = 0.f;
#pragma unroll
            for (int q4 = 0; q4 < 8; ++q4) {
                float4 w = *(const float4*)&w2s[co * 32 + q4 * 4];
                a = fmaf(v1[q4 * 4 + 0], w.x, a); a = fmaf(v1[q4 * 4 + 1], w.y, a);
                a = fmaf(v1[q4 * 4 + 2], w.z, a); a = fmaf(v1[q4 * 4 + 3], w.w, a);
            }
            float v = fmaxf(0.f, fmaf(a, p2[co * 2], p2[co * 2 + 1]));
            hv[j] = (f16)v;
        }
        if (c8 < 4) *(f16x8*)(oa + c8 * 8) = hv;
        else        *(f16x8*)(ob + (c8 - 4) * 8) = hv;
    }
}

// ---- weight prep: OIHW fp32 -> fp16 fragment-lane-ordered, ks-contiguous ----
// frag index fr = ks*18 + tap*2 + cf; lane (p,g): co=cf*16+p, ci=ks*32+g*8+j
template <int CI>
__global__ void k_wprep(const float* __restrict__ w, float* __restrict__ wsg) {
    constexpr int KS = CI / 32;
    int t = blockIdx.x * 256 + threadIdx.x;
    if (t >= KS * 18 * 64) return;
    int lane = t & 63, fr = t >> 6;
    int cf = fr & 1, tap = (fr >> 1) % 9, ks = fr / 18;
    int g = lane >> 4, p = lane & 15;
    int co = cf * 16 + p;
    f16x8 hv;
#pragma unroll
    for (int j = 0; j < 8; ++j) {
        int ci = ks * 32 + g * 8 + j;
        hv[j] = (f16)w[(co * CI + ci) * 9 + tap];
    }
    ((f16x8*)wsg)[fr * 64 + lane] = hv;
}

// ------ Pass 3/4: 3x3 conv, LDS-staged A-tile, single-fp16 MFMA ------
// 512 thr = 8 waves; block tile = 4 rows x 128 px x 32 co; wave: (row, x-half).
// MFMA operands swapped: A=weights(m=co), B=pixels(n=px) -> lane holds 4
// consecutive co per acc frag -> 8B packed stores.
template <int CI, int BNSTAGE>
__global__ __launch_bounds__(512, 4) void k_conv3(const f16* __restrict__ in0,
                                                  const f16* __restrict__ in1,
                                                  const float* __restrict__ wsg,
                                                  const float* __restrict__ prm,
                                                  f16* __restrict__ outp,
                                                  float* __restrict__ bkt) {
    constexpr int KS = CI / 32;
    __shared__ __align__(16) struct {
        f16   Wl[18 * 512];      // 18 KB: current ks weight frags
        f16   Al[6 * 128 * 32];  // 48 KB: A tile (rows y0-1..y0+4)
        float red[8][64];        // stats staging (also +overflow guard for Al)
    } sh;
    int tid = threadIdx.x;
    int lane = tid & 63, w = tid >> 6;
    int p = lane & 15, g = lane >> 4;
    int rw = w >> 1, h = w & 1;

    unsigned o = blockIdx.x;
    unsigned xcd = o & 7u, q = o >> 3;
    unsigned rg = q & 31u, grp = q >> 5;
    unsigned b = (grp << 3) | xcd;        // batch pinned to XCD for L2 locality
    int y0 = (int)rg * 4;

    float psc[8], psh[8];
    if (BNSTAGE) {
        int sub = tid & 3;
#pragma unroll
        for (int j = 0; j < 8; ++j) {
            psc[j] = prm[(sub * 8 + j) * 2];
            psh[j] = prm[(sub * 8 + j) * 2 + 1];
        }
    }

    bool mask0 = (h == 0 && p == 0);
    bool mask1 = (h == 1 && p == 15);
    const f16x8 kZ = {0, 0, 0, 0, 0, 0, 0, 0};

    f32x4 acc[4][2];
#pragma unroll
    for (int f = 0; f < 4; ++f)
#pragma unroll
        for (int cf = 0; cf < 2; ++cf) acc[f][cf] = (f32x4){0.f, 0.f, 0.f, 0.f};

    for (int ks = 0; ks < KS; ++ks) {
        if (ks) __syncthreads();          // WAR on LDS reuse
        // ---- stage weights (18 KB linear) ----
#pragma unroll
        for (int c0 = 0; c0 < 1152; c0 += 512) {
            if (c0 + (w << 6) < 1152) {   // wave-uniform guard
                int c = c0 + tid;
                gl_lds16(wsg + (size_t)(ks * 4608 + c * 4), &sh.Wl[c * 8]);
            }
        }
        // ---- stage A rows (6 x 8KB linear; zero rows at image border) ----
        const f16* src = (KS == 2) ? (ks ? in1 : in0) : in0;
        for (int r6 = 0; r6 < 6; ++r6) {
            int yy = y0 - 1 + r6;
            f16* dst = &sh.Al[r6 * 4096 + tid * 8];
            if ((unsigned)yy < 128u) {
                const f16* s = src + ((size_t)(b * 128u + (unsigned)yy) * 128u) * 32 + tid * 8;
                if (BNSTAGE == 0) {
                    gl_lds16(s, dst);
                } else {
                    f16x8 raw = *(const f16x8*)s;
                    f16x8 o8;
#pragma unroll
                    for (int j = 0; j < 8; ++j) {
                        float vv = fmaxf(0.f, fmaf((float)raw[j], psc[j], psh[j]));
                        o8[j] = (f16)vv;
                    }
                    *(f16x8*)dst = o8;
                }
            } else {
                *(f16x8*)dst = kZ;
            }
        }
        __syncthreads();
        // ---- 9 taps x 4 px-frags x 2 co-halves ----
        const f16x8* Wv = (const f16x8*)sh.Wl;
        for (int dyi = 0; dyi < 3; ++dyi) {
            int ar = rw + dyi;
#pragma unroll
            for (int dxi = 0; dxi < 3; ++dxi) {
                int tap = dyi * 3 + dxi;
                f16x8 b0 = Wv[(tap * 2 + 0) * 64 + lane];
                f16x8 b1 = Wv[(tap * 2 + 1) * 64 + lane];
#pragma unroll
                for (int f = 0; f < 4; ++f) {
                    int px = h * 64 + f * 16 + p + dxi - 1;
                    f16x8 a = *(const f16x8*)&sh.Al[(ar * 128 + px) * 32 + g * 8];
                    if (dxi == 0 && f == 0) { if (mask0) a = kZ; }
                    if (dxi == 2 && f == 3) { if (mask1) a = kZ; }
                    acc[f][0] = __builtin_amdgcn_mfma_f32_16x16x32_f16(b0, a, acc[f][0], 0, 0, 0);
                    acc[f][1] = __builtin_amdgcn_mfma_f32_16x16x32_f16(b1, a, acc[f][1], 0, 0, 0);
                }
            }
        }
    }

    // ---- stats: lane(p,g) reg r of half cf holds co = cf*16+g*4+r ----
    float sv[8], qv[8];
#pragma unroll
    for (int cf = 0; cf < 2; ++cf)
#pragma unroll
        for (int r = 0; r < 4; ++r) {
            float s = acc[0][cf][r] + acc[1][cf][r] + acc[2][cf][r] + acc[3][cf][r];
            float qq = acc[0][cf][r] * acc[0][cf][r] + acc[1][cf][r] * acc[1][cf][r] +
                       acc[2][cf][r] * acc[2][cf][r] + acc[3][cf][r] * acc[3][cf][r];
#pragma unroll
            for (int m = 1; m < 16; m <<= 1) {
                s += __shfl_xor(s, m, 64);
                qq += __shfl_xor(qq, m, 64);
            }
            sv[cf * 4 + r] = s; qv[cf * 4 + r] = qq;
        }
    if (p == 0) {
#pragma unroll
        for (int cf = 0; cf < 2; ++cf)
#pragma unroll
            for (int r = 0; r < 4; ++r) {
                int co = cf * 16 + g * 4 + r;
                sh.red[w][co * 2] = sv[cf * 4 + r];
                sh.red[w][co * 2 + 1] = qv[cf * 4 + r];
            }
    }

    // ---- store raw fp16 NHWC: lane packs 4 consecutive co -> 8B stores ----
    unsigned pxb = b * 16384u + (unsigned)((y0 + rw) * 128 + h * 64 + p);
#pragma unroll
    for (int f = 0; f < 4; ++f)
#pragma unroll
        for (int cf = 0; cf < 2; ++cf) {
            f16x4 o4 = { (f16)acc[f][cf][0], (f16)acc[f][cf][1],
                         (f16)acc[f][cf][2], (f16)acc[f][cf][3] };
            *(f16x4*)(outp + (size_t)(pxb + f * 16u) * 32u + (unsigned)(cf * 16 + g * 4)) = o4;
        }

    __syncthreads();
    if (tid < 64) {
        float v = 0.f;
#pragma unroll
        for (int ww = 0; ww < 8; ++ww) v += sh.red[ww][tid];
        atomicAdd(&bkt[(o & 63u) * 64u + (unsigned)tid], v);
    }
}

// ---- Pass 5: BN4+ReLU + fc1/tanh + fc2/tanh + per-batch token-sum of w0 ----
__global__ __launch_bounds__(TPB) void k_fc(const f16* __restrict__ t4,
                                            const float* __restrict__ prm4,
                                            const float* __restrict__ fw1,
                                            const float* __restrict__ fb1,
                                            const float* __restrict__ fw2,
                                            const float* __restrict__ fb2,
                                            float* __restrict__ y0sum) {
    __shared__ __align__(16) float w1s[1024];
    __shared__ __align__(16) float w2s[512];
    __shared__ float b1s[32], b2s[16], p4[64];
    __shared__ float red[4][16];
    int tid = threadIdx.x;
    for (int e = tid; e < 1024; e += TPB) w1s[e] = fw1[e];
    for (int e = tid; e < 512; e += TPB) w2s[e] = fw2[e];
    if (tid < 32) b1s[tid] = fb1[tid];
    if (tid < 16) b2s[tid] = fb2[tid];
    if (tid < 64) p4[tid] = prm4[tid];
    __syncthreads();
    unsigned pid = blockIdx.x * TPB + tid;
    const f16x8* tv = (const f16x8*)(t4 + (size_t)pid * 32);
    float v[32];
#pragma unroll
    for (int c8 = 0; c8 < 4; ++c8) {
        f16x8 raw = tv[c8];
#pragma unroll
        for (int j = 0; j < 8; ++j) {
            int c = c8 * 8 + j;
            v[c] = fmaxf(0.f, fmaf((float)raw[j], p4[c * 2], p4[c * 2 + 1]));
        }
    }
    float hh[32];
#pragma unroll
    for (int j = 0; j < 32; ++j) {
        float a = b1s[j];
#pragma unroll
        for (int c8 = 0; c8 < 8; ++c8) {
            float4 w = *(const float4*)&w1s[j * 32 + c8 * 4];
            a = fmaf(v[c8 * 4 + 0], w.x, a); a = fmaf(v[c8 * 4 + 1], w.y, a);
            a = fmaf(v[c8 * 4 + 2], w.z, a); a = fmaf(v[c8 * 4 + 3], w.w, a);
        }
        hh[j] = tanhf(a);
    }
    unsigned bb = pid >> 14;
    int wv = tid >> 6;
    for (int k = 0; k < 16; ++k) {
        float a = b2s[k];
#pragma unroll
        for (int c8 = 0; c8 < 8; ++c8) {
            float4 w = *(const float4*)&w2s[k * 32 + c8 * 4];
            a = fmaf(hh[c8 * 4 + 0], w.x, a); a = fmaf(hh[c8 * 4 + 1], w.y, a);
            a = fmaf(hh[c8 * 4 + 2], w.z, a); a = fmaf(hh[c8 * 4 + 3], w.w, a);
        }
        a = tanhf(a);
        float s = wave_sum(a);
        if ((tid & 63) == 0) red[wv][k] = s;
    }
    __syncthreads();
    if (tid < 16) {
        float s = red[0][tid] + red[1][tid] + red[2][tid] + red[3][tid];
        atomicAdd(&y0sum[bb * 16u + tid], s);
    }
}

// -------- Pass 6: finalize y0 -> wn, stable argsort, vals/order/wi, Cm, idx --------
__global__ void k_final(const float* __restrict__ y0sum, float* __restrict__ out,
                        float* __restrict__ Cm, int* __restrict__ idxb) {
    int b = threadIdx.x; // 64 threads
    float y0[16]; float nrm = 0.f;
#pragma unroll
    for (int i = 0; i < 16; ++i) { y0[i] = y0sum[b * 16 + i] * (1.0f / 16384.0f); nrm += y0[i] * y0[i]; }
    nrm = sqrtf(nrm);
    float wn[16]; int id[16];
#pragma unroll
    for (int i = 0; i < 16; ++i) { wn[i] = fabsf(y0[i]) * nrm; id[i] = i; }
    for (int i = 1; i < 16; ++i) {
        float k = wn[i]; int ii = id[i]; int j = i - 1;
        while (j >= 0 && wn[j] < k) { wn[j + 1] = wn[j]; id[j + 1] = id[j]; --j; }
        wn[j + 1] = k; id[j + 1] = ii;
    }
    for (int i = 0; i < 16; ++i) {
        out[VALS_OFF + b * 16 + i] = wn[i];
        out[ORDER_OFF + b * 16 + i] = (float)id[i];
    }
    for (int g = 0; g < 5; ++g)
        out[WI_OFF + g * 64 + b] = (wn[g * 3] + wn[g * 3 + 1] + wn[g * 3 + 2]) * (1.0f / 3.0f);
    for (int i = 0; i < 16; ++i)
        for (int j = 0; j < 16; ++j) Cm[b * 256 + i * 16 + j] = y0[i] * y0[j];
    for (int s = 0; s < 15; ++s) idxb[b * 15 + s] = id[s];
}

// -------- Pass 7: read x once -> cgh (Cm @ x) and fi (channel gather) --------
__global__ __launch_bounds__(TPB) void k_out(const float* __restrict__ x,
                                             const float* __restrict__ Cm,
                                             const int* __restrict__ idxb,
                                             float* __restrict__ out) {
    __shared__ float cm[256];
    __shared__ int idl[15];
    int tid = threadIdx.x;
    unsigned b = blockIdx.x >> 6;
    unsigned p = ((blockIdx.x & 63u) << 8) + tid;
    cm[tid] = Cm[b * 256u + tid];
    if (tid < 15) idl[tid] = idxb[b * 15u + tid];
    __syncthreads();
    const float* xp = x + (size_t)b * 16 * HWc + p;
    float xv[16];
#pragma unroll
    for (int j = 0; j < 16; ++j) xv[j] = xp[(size_t)j * HWc];
    float* og = out + CGH_OFF + (size_t)b * 16 * HWc + p;
    for (int i = 0; i < 16; ++i) {
        float a = 0.f;
#pragma unroll
        for (int j = 0; j < 16; ++j) a = fmaf(cm[i * 16 + j], xv[j], a);
        og[(size_t)i * HWc] = a;
    }
#pragma unroll
    for (int s = 0; s < 15; ++s) {
        int ch = idl[s];
        float vv = xp[(size_t)ch * HWc];
        int g = s / 3, r = s - 3 * g;
        out[(size_t)((g * 64 + (int)b) * 3 + r) * HWc + p] = vv;
    }
}

extern "C" void kernel_launch(void* const* d_in, const int* in_sizes, int n_in,
                              void* d_out, int out_size, void* d_ws, size_t ws_size,
                              hipStream_t stream) {
    const float* x    = (const float*)d_in[0];
    const float* w1   = (const float*)d_in[1];
    const float* bn1g = (const float*)d_in[2];  const float* bn1b = (const float*)d_in[3];
    const float* w2   = (const float*)d_in[4];
    const float* bn2g = (const float*)d_in[5];  const float* bn2b = (const float*)d_in[6];
    const float* w3   = (const float*)d_in[7];
    const float* bn3g = (const float*)d_in[8];  const float* bn3b = (const float*)d_in[9];
    const float* w4   = (const float*)d_in[10];
    const float* bn4g = (const float*)d_in[11]; const float* bn4b = (const float*)d_in[12];
    const float* fw1  = (const float*)d_in[13]; const float* fb1  = (const float*)d_in[14];
    const float* fw2  = (const float*)d_in[15]; const float* fb2  = (const float*)d_in[16];
    float* out = (float*)d_out;
    float* wsf = (float*)d_ws;

    // ws layout (float offsets):
    //   t2a @ 0           (16,777,216) : t2 ch 0..31, fp16 NHWC
    //   t2b @ 16,777,216  (16,777,216) : t2 ch 32..63
    //   t3r @ 33,554,432  (16,777,216) : conv3 raw fp16 NHWC (32 ch)
    //   t4h @ 50,331,648  (16,777,216) : conv4 raw fp16 NHWC (32 ch)
    //   acc @ 67,108,864  : buckets / params / Cm / idx / weight frags
    f16*   t2a = (f16*)wsf;
    f16*   t2b = (f16*)(wsf + 16777216);
    f16*   t3r = (f16*)(wsf + 33554432);
    f16*   t4h = (f16*)(wsf + 50331648);
    float* acc = wsf + 67108864;
    float* b1   = acc;           float* b2  = acc + 4096;
    float* b3   = acc + 12288;   float* b4  = acc + 16384;
    float* y0s  = acc + 20480;
    float* pr1  = acc + 21504;   float* pr2 = acc + 21568;
    float* pr3  = acc + 21696;   float* pr4 = acc + 21760;
    float* Cm   = acc + 21824;
    int*   idxb = (int*)(acc + 38208);
    float* wsg3 = acc + 39168;   // 36 frags * 256 floats-of-f16 = 9216 floats
    float* wsg4 = acc + 48384;   // 18 frags = 2304 floats
    size_t need = (size_t)(67108864 + 50688) * 4;
    if (ws_size < need) return;

    hipMemsetAsync(acc, 0, 21504 * 4, stream);  // zero buckets + y0sum each launch

    k_wprep<64><<<9, 256, 0, stream>>>(w3, wsg3);
    k_wprep<32><<<5, 256, 0, stream>>>(w4, wsg4);
    k_stats1<<<4096, TPB, 0, stream>>>(x, w1, b1);
    k_sfin<<<1, 32, 0, stream>>>(b1, bn1g, bn1b, pr1, 32);
    k_conv12a<<<4096, TPB, 0, stream>>>(x, w1, w2, pr1, b2);
    k_sfin<<<1, 64, 0, stream>>>(b2, bn2g, bn2b, pr2, 64);
    k_conv12b<<<4096, TPB, 0, stream>>>(x, w1, w2, pr1, pr2, t2a, t2b);
    k_conv3<64, 0><<<2048, 512, 0, stream>>>(t2a, t2b, wsg3, nullptr, t3r, b3);
    k_sfin<<<1, 32, 0, stream>>>(b3, bn3g, bn3b, pr3, 32);
    k_conv3<32, 1><<<2048, 512, 0, stream>>>(t3r, t3r, wsg4, pr3, t4h, b4);
    k_sfin<<<1, 32, 0, stream>>>(b4, bn4g, bn4b, pr4, 32);
    k_fc<<<4096, TPB, 0, stream>>>(t4h, pr4, fw1, fb1, fw2, fb2, y0s);
    k_final<<<1, 64, 0, stream>>>(y0s, out, Cm, idxb);
    k_out<<<4096, TPB, 0, stream>>>(x, Cm, idxb, out);
}

// Round 4
// 421.513 us; speedup vs baseline: 3.7535x; 1.6509x over previous
//
#include <hip/hip_runtime.h>

#define TPB 256

static constexpr int   HWc  = 16384;                 // 128*128
static constexpr float NINV = 1.0f / 1048576.0f;     // 1/(B*H*W)

static constexpr unsigned FI_OFF    = 0u;
static constexpr unsigned WI_OFF    = 15728640u;
static constexpr unsigned VALS_OFF  = 15728960u;
static constexpr unsigned ORDER_OFF = 15729984u;
static constexpr unsigned CGH_OFF   = 15731008u;

typedef _Float16 f16;
typedef f16   f16x8 __attribute__((ext_vector_type(8)));
typedef f16   f16x4 __attribute__((ext_vector_type(4)));
typedef float f32x4 __attribute__((ext_vector_type(4)));

// async global->LDS, 16B per lane; LDS dest = wave base + lane*16 (linear layout)
__device__ __forceinline__ void gl_lds16(const void* g, void* l) {
    __builtin_amdgcn_global_load_lds(
        (const __attribute__((address_space(1))) unsigned int*)g,
        (__attribute__((address_space(3))) unsigned int*)l, 16, 0, 0);
}

__device__ __forceinline__ float wave_sum(float v) {
#pragma unroll
    for (int o = 1; o < 64; o <<= 1) v += __shfl_xor(v, o, 64);
    return v;
}

// ---- Pass A: Gram of x (16x16) + col sums via MFMA -> stats1 analytically ----
__global__ __launch_bounds__(TPB) void k_gramx(const float* __restrict__ x,
                                               float* __restrict__ bkt) {
    __shared__ float red[4][272];
    int tid = threadIdx.x, lane = tid & 63, w = tid >> 6;
    int p = lane & 15, g = lane >> 4;
    const f16 one = (f16)1.0f;
    const f16x8 kOnes = {one, one, one, one, one, one, one, one};
    f32x4 accG = {0.f, 0.f, 0.f, 0.f};
    f32x4 accS = {0.f, 0.f, 0.f, 0.f};
    unsigned wgid = blockIdx.x * 4u + (unsigned)w;
    for (unsigned c = wgid; c < 32768u; c += 2048u) {   // 32 px per chunk
        unsigned P0 = c * 32u;
        unsigned b = P0 >> 14, off = P0 & 16383u;
        const float* src = x + ((size_t)b * 16 + p) * HWc + off + g * 8;
        float4 a4 = *(const float4*)src;
        float4 b4 = *(const float4*)(src + 4);
        f16x8 f = { (f16)a4.x, (f16)a4.y, (f16)a4.z, (f16)a4.w,
                    (f16)b4.x, (f16)b4.y, (f16)b4.z, (f16)b4.w };
        accG = __builtin_amdgcn_mfma_f32_16x16x32_f16(f, f, accG, 0, 0, 0);
        accS = __builtin_amdgcn_mfma_f32_16x16x32_f16(kOnes, f, accS, 0, 0, 0);
    }
#pragma unroll
    for (int r = 0; r < 4; ++r) red[w][(4 * g + r) * 16 + p] = accG[r];
    if (g == 0) red[w][256 + p] = accS[0];
    __syncthreads();
    for (int e = tid; e < 272; e += TPB) {
        float v = red[0][e] + red[1][e] + red[2][e] + red[3][e];
        atomicAdd(&bkt[(blockIdx.x & 63u) * 272u + (unsigned)e], v);
    }
}

// ---- stats1 finalize: G_x -> mean/var of conv1 raw -> (scale, shift) ----
__global__ void k_sfin1g(const float* __restrict__ bkt, const float* __restrict__ w1,
                         const float* __restrict__ g1, const float* __restrict__ bb1,
                         float* __restrict__ prm) {
    __shared__ float G[256];
    __shared__ float S[16];
    int tid = threadIdx.x;   // 256
    {
        float v = 0.f;
        for (int s = 0; s < 64; ++s) v += bkt[s * 272 + tid];
        G[tid] = v;
    }
    if (tid < 16) {
        float v = 0.f;
        for (int s = 0; s < 64; ++s) v += bkt[s * 272 + 256 + tid];
        S[tid] = v;
    }
    __syncthreads();
    if (tid < 32) {
        float wv[16];
#pragma unroll
        for (int i = 0; i < 16; ++i) wv[i] = w1[tid * 16 + i];
        float m = 0.f, e2 = 0.f;
#pragma unroll
        for (int i = 0; i < 16; ++i) {
            m += wv[i] * S[i];
            float t = 0.f;
#pragma unroll
            for (int j = 0; j < 16; ++j) t += wv[j] * G[i * 16 + j];
            e2 += wv[i] * t;
        }
        float mean = m * NINV;
        float var = e2 * NINV - mean * mean;
        float sc = g1[tid] * rsqrtf(var + 1e-5f);
        prm[tid * 2] = sc;
        prm[tid * 2 + 1] = bb1[tid] - mean * sc;
    }
}

// ---- Pass B: conv1 scalar + BN1/ReLU -> v1 fp16 -> LDS -> MFMA conv2 raw out
//      + MFMA Gram(v1) for stats2. No shuffles, no stats recompute pass. ----
__global__ __launch_bounds__(TPB) void k_conv2m(const float* __restrict__ x,
                                                const float* __restrict__ w1,
                                                const float* __restrict__ w2,
                                                const float* __restrict__ prm1,
                                                f16* __restrict__ t2r,
                                                float* __restrict__ bkt) {
    __shared__ __align__(16) float w1s[512];
    __shared__ float p1[64];
    __shared__ __align__(16) f16 V[256 * 40];   // [px][32ch] pad->40
    __shared__ float red[4][800];
    int tid = threadIdx.x, lane = tid & 63, w = tid >> 6;
    int p = lane & 15, g = lane >> 4;
    for (int e = tid; e < 512; e += TPB) w1s[e] = w1[e];
    if (tid < 64) p1[tid] = prm1[tid];
    // W2 fragments: lane (p,g) of block cb holds W2[cb*16+p][g*8..+7] fp16
    f16x8 Wf[4];
#pragma unroll
    for (int cb = 0; cb < 4; ++cb) {
        const float* wr = w2 + (cb * 16 + p) * 32 + g * 8;
        float4 a4 = *(const float4*)wr;
        float4 b4 = *(const float4*)(wr + 4);
        Wf[cb] = (f16x8){ (f16)a4.x, (f16)a4.y, (f16)a4.z, (f16)a4.w,
                          (f16)b4.x, (f16)b4.y, (f16)b4.z, (f16)b4.w };
    }
    __syncthreads();
    unsigned pid = blockIdx.x * TPB + tid;
    const float* xp = x + (size_t)(pid >> 14) * 16 * HWc + (pid & 16383u);
    float xv[16];
#pragma unroll
    for (int c = 0; c < 16; ++c) xv[c] = xp[(size_t)c * HWc];
    f16* vp = V + tid * 40;
#pragma unroll
    for (int c8 = 0; c8 < 4; ++c8) {
        f16x8 hv;
#pragma unroll
        for (int j = 0; j < 8; ++j) {
            int co = c8 * 8 + j;
            float a = 0.f;
#pragma unroll
            for (int c4 = 0; c4 < 4; ++c4) {
                float4 ww = *(const float4*)&w1s[co * 16 + c4 * 4];
                a = fmaf(xv[c4 * 4 + 0], ww.x, a); a = fmaf(xv[c4 * 4 + 1], ww.y, a);
                a = fmaf(xv[c4 * 4 + 2], ww.z, a); a = fmaf(xv[c4 * 4 + 3], ww.w, a);
            }
            hv[j] = (f16)fmaxf(0.f, fmaf(a, p1[co * 2], p1[co * 2 + 1]));
        }
        *(f16x8*)(vp + c8 * 8) = hv;
    }
    __syncthreads();
    // conv2: wave w owns px [w*64, w*64+64)
    unsigned Pb = blockIdx.x * TPB + (unsigned)(w * 64);
#pragma unroll
    for (int f = 0; f < 4; ++f) {
        int pxl = w * 64 + f * 16 + p;
        f16x8 bf = *(const f16x8*)&V[pxl * 40 + g * 8];
        unsigned Pg = Pb + (unsigned)(f * 16 + p);
#pragma unroll
        for (int cb = 0; cb < 4; ++cb) {
            f32x4 d = {0.f, 0.f, 0.f, 0.f};
            d = __builtin_amdgcn_mfma_f32_16x16x32_f16(Wf[cb], bf, d, 0, 0, 0);
            f16x4 o4 = { (f16)d[0], (f16)d[1], (f16)d[2], (f16)d[3] };
            *(f16x4*)(t2r + (size_t)Pg * 64 + cb * 16 + 4 * g) = o4;
        }
    }
    // Gram(v1): 32x32 in 3 blocks (0,0),(0,1),(1,1) + col sums
    const f16 one = (f16)1.0f;
    const f16x8 kOnes = {one, one, one, one, one, one, one, one};
    f32x4 accG[3] = {{0.f,0.f,0.f,0.f},{0.f,0.f,0.f,0.f},{0.f,0.f,0.f,0.f}};
    f32x4 accS[2] = {{0.f,0.f,0.f,0.f},{0.f,0.f,0.f,0.f}};
#pragma unroll
    for (int c2 = 0; c2 < 2; ++c2) {
        int px0 = w * 64 + c2 * 32;
        f16x8 fb[2];
#pragma unroll
        for (int cb2 = 0; cb2 < 2; ++cb2)
#pragma unroll
            for (int j = 0; j < 8; ++j)
                fb[cb2][j] = V[(px0 + g * 8 + j) * 40 + cb2 * 16 + p];
        accG[0] = __builtin_amdgcn_mfma_f32_16x16x32_f16(fb[0], fb[0], accG[0], 0, 0, 0);
        accG[1] = __builtin_amdgcn_mfma_f32_16x16x32_f16(fb[0], fb[1], accG[1], 0, 0, 0);
        accG[2] = __builtin_amdgcn_mfma_f32_16x16x32_f16(fb[1], fb[1], accG[2], 0, 0, 0);
        accS[0] = __builtin_amdgcn_mfma_f32_16x16x32_f16(kOnes, fb[0], accS[0], 0, 0, 0);
        accS[1] = __builtin_amdgcn_mfma_f32_16x16x32_f16(kOnes, fb[1], accS[1], 0, 0, 0);
    }
#pragma unroll
    for (int blk = 0; blk < 3; ++blk)
#pragma unroll
        for (int r = 0; r < 4; ++r)
            red[w][blk * 256 + (4 * g + r) * 16 + p] = accG[blk][r];
    if (g == 0) { red[w][768 + p] = accS[0][0]; red[w][784 + p] = accS[1][0]; }
    __syncthreads();
    for (int e = tid; e < 800; e += TPB) {
        float v = red[0][e] + red[1][e] + red[2][e] + red[3][e];
        atomicAdd(&bkt[(blockIdx.x & 63u) * 800u + (unsigned)e], v);
    }
}

// ---- stats2 finalize: Gram(v1) -> mean/var of conv2 raw (fp16-consistent W2) ----
__global__ void k_sfin2g(const float* __restrict__ bkt, const float* __restrict__ w2,
                         const float* __restrict__ g2, const float* __restrict__ bb2,
                         float* __restrict__ prm) {
    __shared__ float G[768];
    __shared__ float S[32];
    int tid = threadIdx.x;   // 256
    for (int e = tid; e < 768; e += 256) {
        float v = 0.f;
        for (int s = 0; s < 64; ++s) v += bkt[s * 800 + e];
        G[e] = v;
    }
    if (tid < 32) {
        float v = 0.f;
        for (int s = 0; s < 64; ++s) v += bkt[s * 800 + 768 + tid];
        S[tid] = v;
    }
    __syncthreads();
    if (tid < 64) {
        float wv[32];
#pragma unroll
        for (int i = 0; i < 32; ++i) wv[i] = (float)(f16)w2[tid * 32 + i];
        float m = 0.f, e2 = 0.f;
#pragma unroll
        for (int i = 0; i < 32; ++i) {
            m += wv[i] * S[i];
            int bi = i >> 4, il = i & 15;
            float t = 0.f;
#pragma unroll
            for (int j = 0; j < 32; ++j) {
                int bj = j >> 4, jl = j & 15;
                float Gij;
                if (bi <= bj) Gij = G[(bi == 0 ? (bj == 0 ? 0 : 1) : 2) * 256 + il * 16 + jl];
                else          Gij = G[(bj == 0 ? 1 : 2) * 256 + jl * 16 + il];
                t += wv[j] * Gij;
            }
            e2 += wv[i] * t;
        }
        float mean = m * NINV;
        float var = e2 * NINV - mean * mean;
        float sc = g2[tid] * rsqrtf(var + 1e-5f);
        prm[tid * 2] = sc;
        prm[tid * 2 + 1] = bb2[tid] - mean * sc;
    }
}

// ------------- generic stats finalize (sum/sumsq buckets, conv3/conv4) -------------
__global__ void k_sfin(const float* __restrict__ bkt, const float* __restrict__ g,
                       const float* __restrict__ bb, float* __restrict__ prm, int C) {
    int co = threadIdx.x;
    float s = 0.f, q = 0.f;
    for (int k = 0; k < 64; ++k) { s += bkt[(k * C + co) * 2]; q += bkt[(k * C + co) * 2 + 1]; }
    float mean = s * NINV;
    float var = q * NINV - mean * mean;
    float sc = g[co] * rsqrtf(var + 1e-5f);
    prm[co * 2] = sc;
    prm[co * 2 + 1] = bb[co] - mean * sc;
}

// ---- weight prep: OIHW fp32 -> fp16 fragment-lane-ordered, ks-contiguous ----
template <int CI>
__global__ void k_wprep(const float* __restrict__ w, float* __restrict__ wsg) {
    constexpr int KS = CI / 32;
    int t = blockIdx.x * 256 + threadIdx.x;
    if (t >= KS * 18 * 64) return;
    int lane = t & 63, fr = t >> 6;
    int cf = fr & 1, tap = (fr >> 1) % 9, ks = fr / 18;
    int g = lane >> 4, p = lane & 15;
    int co = cf * 16 + p;
    f16x8 hv;
#pragma unroll
    for (int j = 0; j < 8; ++j) {
        int ci = ks * 32 + g * 8 + j;
        hv[j] = (f16)w[(co * CI + ci) * 9 + tap];
    }
    ((f16x8*)wsg)[fr * 64 + lane] = hv;
}

// ------ Pass C/D: 3x3 conv, BN+ReLU fused on LDS staging, MFMA ------
// input: raw fp16 NHWC [px][CI]; 512 thr; block tile 4 rows x 128 px x 32 co.
template <int CI>
__global__ __launch_bounds__(512, 4) void k_conv3(const f16* __restrict__ in,
                                                  const float* __restrict__ wsg,
                                                  const float* __restrict__ prm,
                                                  f16* __restrict__ outp,
                                                  float* __restrict__ bkt) {
    constexpr int KS = CI / 32;
    __shared__ __align__(16) struct {
        f16   Wl[18 * 512];      // 18 KB: current ks weight frags
        f16   Al[6 * 128 * 32];  // 48 KB: BN'd A tile (rows y0-1..y0+4)
        float red[8][64];
    } sh;
    int tid = threadIdx.x;
    int lane = tid & 63, w = tid >> 6;
    int p = lane & 15, g = lane >> 4;
    int rw = w >> 1, h = w & 1;
    int cw = tid & 3, pxt = tid >> 2;

    unsigned o = blockIdx.x;
    unsigned xcd = o & 7u, q = o >> 3;
    unsigned rg = q & 31u, grp = q >> 5;
    unsigned b = (grp << 3) | xcd;        // batch pinned to XCD for L2 locality
    int y0 = (int)rg * 4;

    float psc[KS][8], psh[KS][8];
#pragma unroll
    for (int ks = 0; ks < KS; ++ks)
#pragma unroll
        for (int j = 0; j < 8; ++j) {
            int ch = ks * 32 + cw * 8 + j;
            psc[ks][j] = prm[ch * 2];
            psh[ks][j] = prm[ch * 2 + 1];
        }

    bool mask0 = (h == 0 && p == 0);
    bool mask1 = (h == 1 && p == 15);
    const f16x8 kZ = {0, 0, 0, 0, 0, 0, 0, 0};

    f32x4 acc[4][2];
#pragma unroll
    for (int f = 0; f < 4; ++f)
#pragma unroll
        for (int cf = 0; cf < 2; ++cf) acc[f][cf] = (f32x4){0.f, 0.f, 0.f, 0.f};

    for (int ks = 0; ks < KS; ++ks) {
        if (ks) __syncthreads();          // WAR on LDS reuse
        // ---- stage weights (18 KB linear, async) ----
#pragma unroll
        for (int c0 = 0; c0 < 1152; c0 += 512) {
            if (c0 + (w << 6) < 1152) {   // wave-uniform guard
                int c = c0 + tid;
                gl_lds16(wsg + (size_t)(ks * 4608 + c * 4), &sh.Wl[c * 8]);
            }
        }
        // ---- stage A rows, BN+ReLU applied; zero at image border ----
#pragma unroll
        for (int r6 = 0; r6 < 6; ++r6) {
            int yy = y0 - 1 + r6;
            f16* dst = &sh.Al[r6 * 4096 + tid * 8];
            if ((unsigned)yy < 128u) {
                const f16* s = in + ((size_t)(b * 128u + (unsigned)yy) * 128u + pxt) * CI
                                  + ks * 32 + cw * 8;
                f16x8 raw = *(const f16x8*)s;
                f16x8 o8;
#pragma unroll
                for (int j = 0; j < 8; ++j)
                    o8[j] = (f16)fmaxf(0.f, fmaf((float)raw[j], psc[ks][j], psh[ks][j]));
                *(f16x8*)dst = o8;
            } else {
                *(f16x8*)dst = kZ;
            }
        }
        __syncthreads();
        // ---- 9 taps x 4 px-frags x 2 co-halves ----
        const f16x8* Wv = (const f16x8*)sh.Wl;
        for (int dyi = 0; dyi < 3; ++dyi) {
            int ar = rw + dyi;
#pragma unroll
            for (int dxi = 0; dxi < 3; ++dxi) {
                int tap = dyi * 3 + dxi;
                f16x8 b0 = Wv[(tap * 2 + 0) * 64 + lane];
                f16x8 b1 = Wv[(tap * 2 + 1) * 64 + lane];
#pragma unroll
                for (int f = 0; f < 4; ++f) {
                    int px = h * 64 + f * 16 + p + dxi - 1;
                    f16x8 a = *(const f16x8*)&sh.Al[(ar * 128 + px) * 32 + g * 8];
                    if (dxi == 0 && f == 0) { if (mask0) a = kZ; }
                    if (dxi == 2 && f == 3) { if (mask1) a = kZ; }
                    acc[f][0] = __builtin_amdgcn_mfma_f32_16x16x32_f16(b0, a, acc[f][0], 0, 0, 0);
                    acc[f][1] = __builtin_amdgcn_mfma_f32_16x16x32_f16(b1, a, acc[f][1], 0, 0, 0);
                }
            }
        }
    }

    // ---- stats: lane(p,g) reg r of half cf holds co = cf*16+g*4+r ----
    float sv[8], qv[8];
#pragma unroll
    for (int cf = 0; cf < 2; ++cf)
#pragma unroll
        for (int r = 0; r < 4; ++r) {
            float s = acc[0][cf][r] + acc[1][cf][r] + acc[2][cf][r] + acc[3][cf][r];
            float qq = acc[0][cf][r] * acc[0][cf][r] + acc[1][cf][r] * acc[1][cf][r] +
                       acc[2][cf][r] * acc[2][cf][r] + acc[3][cf][r] * acc[3][cf][r];
#pragma unroll
            for (int m = 1; m < 16; m <<= 1) {
                s += __shfl_xor(s, m, 64);
                qq += __shfl_xor(qq, m, 64);
            }
            sv[cf * 4 + r] = s; qv[cf * 4 + r] = qq;
        }
    if (p == 0) {
#pragma unroll
        for (int cf = 0; cf < 2; ++cf)
#pragma unroll
            for (int r = 0; r < 4; ++r) {
                int co = cf * 16 + g * 4 + r;
                sh.red[w][co * 2] = sv[cf * 4 + r];
                sh.red[w][co * 2 + 1] = qv[cf * 4 + r];
            }
    }

    // ---- store raw fp16 NHWC: lane packs 4 consecutive co -> 8B stores ----
    unsigned pxb = b * 16384u + (unsigned)((y0 + rw) * 128 + h * 64 + p);
#pragma unroll
    for (int f = 0; f < 4; ++f)
#pragma unroll
        for (int cf = 0; cf < 2; ++cf) {
            f16x4 o4 = { (f16)acc[f][cf][0], (f16)acc[f][cf][1],
                         (f16)acc[f][cf][2], (f16)acc[f][cf][3] };
            *(f16x4*)(outp + (size_t)(pxb + f * 16u) * 32u + (unsigned)(cf * 16 + g * 4)) = o4;
        }

    __syncthreads();
    if (tid < 64) {
        float v = 0.f;
#pragma unroll
        for (int ww = 0; ww < 8; ++ww) v += sh.red[ww][tid];
        atomicAdd(&bkt[(o & 63u) * 64u + (unsigned)tid], v);
    }
}

// ---- Pass E: BN4+ReLU + fc1/tanh + fc2/tanh + per-batch token-sum of w0 ----
__global__ __launch_bounds__(TPB) void k_fc(const f16* __restrict__ t4,
                                            const float* __restrict__ prm4,
                                            const float* __restrict__ fw1,
                                            const float* __restrict__ fb1,
                                            const float* __restrict__ fw2,
                                            const float* __restrict__ fb2,
                                            float* __restrict__ y0sum) {
    __shared__ __align__(16) float w1s[1024];
    __shared__ __align__(16) float w2s[512];
    __shared__ float b1s[32], b2s[16], p4[64];
    __shared__ float red[4][16];
    int tid = threadIdx.x;
    for (int e = tid; e < 1024; e += TPB) w1s[e] = fw1[e];
    for (int e = tid; e < 512; e += TPB) w2s[e] = fw2[e];
    if (tid < 32) b1s[tid] = fb1[tid];
    if (tid < 16) b2s[tid] = fb2[tid];
    if (tid < 64) p4[tid] = prm4[tid];
    __syncthreads();
    unsigned pid = blockIdx.x * TPB + tid;
    const f16x8* tv = (const f16x8*)(t4 + (size_t)pid * 32);
    float v[32];
#pragma unroll
    for (int c8 = 0; c8 < 4; ++c8) {
        f16x8 raw = tv[c8];
#pragma unroll
        for (int j = 0; j < 8; ++j) {
            int c = c8 * 8 + j;
            v[c] = fmaxf(0.f, fmaf((float)raw[j], p4[c * 2], p4[c * 2 + 1]));
        }
    }
    float hh[32];
#pragma unroll
    for (int j = 0; j < 32; ++j) {
        float a = b1s[j];
#pragma unroll
        for (int c8 = 0; c8 < 8; ++c8) {
            float4 w = *(const float4*)&w1s[j * 32 + c8 * 4];
            a = fmaf(v[c8 * 4 + 0], w.x, a); a = fmaf(v[c8 * 4 + 1], w.y, a);
            a = fmaf(v[c8 * 4 + 2], w.z, a); a = fmaf(v[c8 * 4 + 3], w.w, a);
        }
        hh[j] = tanhf(a);
    }
    unsigned bb = pid >> 14;
    int wv = tid >> 6;
    for (int k = 0; k < 16; ++k) {
        float a = b2s[k];
#pragma unroll
        for (int c8 = 0; c8 < 8; ++c8) {
            float4 w = *(const float4*)&w2s[k * 32 + c8 * 4];
            a = fmaf(hh[c8 * 4 + 0], w.x, a); a = fmaf(hh[c8 * 4 + 1], w.y, a);
            a = fmaf(hh[c8 * 4 + 2], w.z, a); a = fmaf(hh[c8 * 4 + 3], w.w, a);
        }
        a = tanhf(a);
        float s = wave_sum(a);
        if ((tid & 63) == 0) red[wv][k] = s;
    }
    __syncthreads();
    if (tid < 16) {
        float s = red[0][tid] + red[1][tid] + red[2][tid] + red[3][tid];
        atomicAdd(&y0sum[bb * 16u + tid], s);
    }
}

// -------- finalize y0 -> wn, stable argsort, vals/order/wi, Cm, idx --------
__global__ void k_final(const float* __restrict__ y0sum, float* __restrict__ out,
                        float* __restrict__ Cm, int* __restrict__ idxb) {
    int b = threadIdx.x; // 64 threads
    float y0[16]; float nrm = 0.f;
#pragma unroll
    for (int i = 0; i < 16; ++i) { y0[i] = y0sum[b * 16 + i] * (1.0f / 16384.0f); nrm += y0[i] * y0[i]; }
    nrm = sqrtf(nrm);
    float wn[16]; int id[16];
#pragma unroll
    for (int i = 0; i < 16; ++i) { wn[i] = fabsf(y0[i]) * nrm; id[i] = i; }
    for (int i = 1; i < 16; ++i) {
        float k = wn[i]; int ii = id[i]; int j = i - 1;
        while (j >= 0 && wn[j] < k) { wn[j + 1] = wn[j]; id[j + 1] = id[j]; --j; }
        wn[j + 1] = k; id[j + 1] = ii;
    }
    for (int i = 0; i < 16; ++i) {
        out[VALS_OFF + b * 16 + i] = wn[i];
        out[ORDER_OFF + b * 16 + i] = (float)id[i];
    }
    for (int g = 0; g < 5; ++g)
        out[WI_OFF + g * 64 + b] = (wn[g * 3] + wn[g * 3 + 1] + wn[g * 3 + 2]) * (1.0f / 3.0f);
    for (int i = 0; i < 16; ++i)
        for (int j = 0; j < 16; ++j) Cm[b * 256 + i * 16 + j] = y0[i] * y0[j];
    for (int s = 0; s < 15; ++s) idxb[b * 15 + s] = id[s];
}

// -------- read x once -> cgh (Cm @ x) and fi (channel gather) --------
__global__ __launch_bounds__(TPB) void k_out(const float* __restrict__ x,
                                             const float* __restrict__ Cm,
                                             const int* __restrict__ idxb,
                                             float* __restrict__ out) {
    __shared__ float cm[256];
    __shared__ int idl[15];
    int tid = threadIdx.x;
    unsigned b = blockIdx.x >> 6;
    unsigned p = ((blockIdx.x & 63u) << 8) + tid;
    cm[tid] = Cm[b * 256u + tid];
    if (tid < 15) idl[tid] = idxb[b * 15u + tid];
    __syncthreads();
    const float* xp = x + (size_t)b * 16 * HWc + p;
    float xv[16];
#pragma unroll
    for (int j = 0; j < 16; ++j) xv[j] = xp[(size_t)j * HWc];
    float* og = out + CGH_OFF + (size_t)b * 16 * HWc + p;
    for (int i = 0; i < 16; ++i) {
        float a = 0.f;
#pragma unroll
        for (int j = 0; j < 16; ++j) a = fmaf(cm[i * 16 + j], xv[j], a);
        og[(size_t)i * HWc] = a;
    }
#pragma unroll
    for (int s = 0; s < 15; ++s) {
        int ch = idl[s];
        float vv = xp[(size_t)ch * HWc];
        int g = s / 3, r = s - 3 * g;
        out[(size_t)((g * 64 + (int)b) * 3 + r) * HWc + p] = vv;
    }
}

extern "C" void kernel_launch(void* const* d_in, const int* in_sizes, int n_in,
                              void* d_out, int out_size, void* d_ws, size_t ws_size,
                              hipStream_t stream) {
    const float* x    = (const float*)d_in[0];
    const float* w1   = (const float*)d_in[1];
    const float* bn1g = (const float*)d_in[2];  const float* bn1b = (const float*)d_in[3];
    const float* w2   = (const float*)d_in[4];
    const float* bn2g = (const float*)d_in[5];  const float* bn2b = (const float*)d_in[6];
    const float* w3   = (const float*)d_in[7];
    const float* bn3g = (const float*)d_in[8];  const float* bn3b = (const float*)d_in[9];
    const float* w4   = (const float*)d_in[10];
    const float* bn4g = (const float*)d_in[11]; const float* bn4b = (const float*)d_in[12];
    const float* fw1  = (const float*)d_in[13]; const float* fb1  = (const float*)d_in[14];
    const float* fw2  = (const float*)d_in[15]; const float* fb2  = (const float*)d_in[16];
    float* out = (float*)d_out;
    float* wsf = (float*)d_ws;

    // ws layout (float offsets):
    //   t2r @ 0           (33,554,432) : conv2 raw fp16 NHWC [px][64]
    //   t3r @ 33,554,432  (16,777,216) : conv3 raw fp16 NHWC [px][32]
    //   t4h @ 50,331,648  (16,777,216) : conv4 raw fp16 NHWC [px][32]
    //   acc @ 67,108,864  : buckets / params / Cm / idx / weight frags
    f16*   t2r = (f16*)wsf;
    f16*   t3r = (f16*)(wsf + 33554432);
    f16*   t4h = (f16*)(wsf + 50331648);
    float* acc = wsf + 67108864;
    float* b1g = acc;                 // 64*272 = 17408
    float* b2g = acc + 17408;         // 64*800 = 51200
    float* b3  = acc + 68608;         // 8192
    float* b4  = acc + 76800;         // 8192
    float* y0s = acc + 84992;         // 1024   (zeroed range ends at 86016)
    float* pr1 = acc + 86016;  float* pr2 = acc + 86080;
    float* pr3 = acc + 86208;  float* pr4 = acc + 86272;
    float* Cm  = acc + 86336;         // 16384
    int*   idxb = (int*)(acc + 102720); // 960
    float* wsg3 = acc + 103680;       // 9216 floats (36 frags)
    float* wsg4 = acc + 112896;       // 4608 floats (18 frags)
    size_t need = (size_t)(67108864 + 117504) * 4;
    if (ws_size < need) return;

    hipMemsetAsync(acc, 0, 86016 * 4, stream);  // zero all stat buckets + y0sum

    k_wprep<64><<<9, 256, 0, stream>>>(w3, wsg3);
    k_wprep<32><<<5, 256, 0, stream>>>(w4, wsg4);
    k_gramx<<<512, TPB, 0, stream>>>(x, b1g);
    k_sfin1g<<<1, 256, 0, stream>>>(b1g, w1, bn1g, bn1b, pr1);
    k_conv2m<<<4096, TPB, 0, stream>>>(x, w1, w2, pr1, t2r, b2g);
    k_sfin2g<<<1, 256, 0, stream>>>(b2g, w2, bn2g, bn2b, pr2);
    k_conv3<64><<<2048, 512, 0, stream>>>(t2r, wsg3, pr2, t3r, b3);
    k_sfin<<<1, 32, 0, stream>>>(b3, bn3g, bn3b, pr3, 32);
    k_conv3<32><<<2048, 512, 0, stream>>>(t3r, wsg4, pr3, t4h, b4);
    k_sfin<<<1, 32, 0, stream>>>(b4, bn4g, bn4b, pr4, 32);
    k_fc<<<4096, TPB, 0, stream>>>(t4h, pr4, fw1, fb1, fw2, fb2, y0s);
    k_final<<<1, 64, 0, stream>>>(y0s, out, Cm, idxb);
    k_out<<<4096, TPB, 0, stream>>>(x, Cm, idxb, out);
}

// Round 6
// 365.635 us; speedup vs baseline: 4.3271x; 1.1528x over previous
//
#include <hip/hip_runtime.h>

#define TPB 256

static constexpr int   HWc  = 16384;                 // 128*128
static constexpr float NINV = 1.0f / 1048576.0f;     // 1/(B*H*W)

static constexpr unsigned FI_OFF    = 0u;
static constexpr unsigned WI_OFF    = 15728640u;
static constexpr unsigned VALS_OFF  = 15728960u;
static constexpr unsigned ORDER_OFF = 15729984u;
static constexpr unsigned CGH_OFF   = 15731008u;

typedef _Float16 f16;
typedef f16   f16x8 __attribute__((ext_vector_type(8)));
typedef f16   f16x4 __attribute__((ext_vector_type(4)));
typedef float f32x4 __attribute__((ext_vector_type(4)));

// async global->LDS, 16B per lane; LDS dest = wave base + lane*16 (linear layout)
__device__ __forceinline__ void gl_lds16(const void* g, void* l) {
    __builtin_amdgcn_global_load_lds(
        (const __attribute__((address_space(1))) unsigned int*)g,
        (__attribute__((address_space(3))) unsigned int*)l, 16, 0, 0);
}

__device__ __forceinline__ float wave_sum(float v) {
#pragma unroll
    for (int o = 1; o < 64; o <<= 1) v += __shfl_xor(v, o, 64);
    return v;
}

// fast tanh: 1 - 2/(e^{2x}+1); v_exp_f32 + v_rcp_f32, ~1e-6 rel, exact saturation
__device__ __forceinline__ float tanh_fast(float x) {
    float e = __expf(x + x);
    return 1.0f - __fdividef(2.0f, e + 1.0f);
}

// ---- Pass A: Gram of x (16x16) + col sums via MFMA -> stats1 analytically ----
__global__ __launch_bounds__(TPB) void k_gramx(const float* __restrict__ x,
                                               float* __restrict__ bkt) {
    __shared__ float red[4][272];
    int tid = threadIdx.x, lane = tid & 63, w = tid >> 6;
    int p = lane & 15, g = lane >> 4;
    const f16 one = (f16)1.0f;
    const f16x8 kOnes = {one, one, one, one, one, one, one, one};
    f32x4 accG = {0.f, 0.f, 0.f, 0.f};
    f32x4 accS = {0.f, 0.f, 0.f, 0.f};
    unsigned wgid = blockIdx.x * 4u + (unsigned)w;
    for (unsigned c = wgid; c < 32768u; c += 2048u) {   // 32 px per chunk
        unsigned P0 = c * 32u;
        unsigned b = P0 >> 14, off = P0 & 16383u;
        const float* src = x + ((size_t)b * 16 + p) * HWc + off + g * 8;
        float4 a4 = *(const float4*)src;
        float4 b4 = *(const float4*)(src + 4);
        f16x8 f = { (f16)a4.x, (f16)a4.y, (f16)a4.z, (f16)a4.w,
                    (f16)b4.x, (f16)b4.y, (f16)b4.z, (f16)b4.w };
        accG = __builtin_amdgcn_mfma_f32_16x16x32_f16(f, f, accG, 0, 0, 0);
        accS = __builtin_amdgcn_mfma_f32_16x16x32_f16(kOnes, f, accS, 0, 0, 0);
    }
#pragma unroll
    for (int r = 0; r < 4; ++r) red[w][(4 * g + r) * 16 + p] = accG[r];
    if (g == 0) red[w][256 + p] = accS[0];
    __syncthreads();
    for (int e = tid; e < 272; e += TPB) {
        float v = red[0][e] + red[1][e] + red[2][e] + red[3][e];
        atomicAdd(&bkt[(blockIdx.x & 63u) * 272u + (unsigned)e], v);
    }
}

// ---- stats1 finalize: G_x -> mean/var of conv1 raw -> (scale, shift) ----
__global__ void k_sfin1g(const float* __restrict__ bkt, const float* __restrict__ w1,
                         const float* __restrict__ g1, const float* __restrict__ bb1,
                         float* __restrict__ prm) {
    __shared__ float G[256];
    __shared__ float S[16];
    int tid = threadIdx.x;   // 256
    {
        float v = 0.f;
        for (int s = 0; s < 64; ++s) v += bkt[s * 272 + tid];
        G[tid] = v;
    }
    if (tid < 16) {
        float v = 0.f;
        for (int s = 0; s < 64; ++s) v += bkt[s * 272 + 256 + tid];
        S[tid] = v;
    }
    __syncthreads();
    if (tid < 32) {
        float wv[16];
#pragma unroll
        for (int i = 0; i < 16; ++i) wv[i] = w1[tid * 16 + i];
        float m = 0.f, e2 = 0.f;
#pragma unroll
        for (int i = 0; i < 16; ++i) {
            m += wv[i] * S[i];
            float t = 0.f;
#pragma unroll
            for (int j = 0; j < 16; ++j) t += wv[j] * G[i * 16 + j];
            e2 += wv[i] * t;
        }
        float mean = m * NINV;
        float var = e2 * NINV - mean * mean;
        float sc = g1[tid] * rsqrtf(var + 1e-5f);
        prm[tid * 2] = sc;
        prm[tid * 2 + 1] = bb1[tid] - mean * sc;
    }
}

// ---- Pass B: conv1 scalar + BN1/ReLU -> v1 fp16 -> LDS -> MFMA conv2 raw out
//      + MFMA Gram(v1) for stats2. ----
__global__ __launch_bounds__(TPB) void k_conv2m(const float* __restrict__ x,
                                                const float* __restrict__ w1,
                                                const float* __restrict__ w2,
                                                const float* __restrict__ prm1,
                                                f16* __restrict__ t2r,
                                                float* __restrict__ bkt) {
    __shared__ __align__(16) float w1s[512];
    __shared__ float p1[64];
    __shared__ __align__(16) f16 V[256 * 40];   // [px][32ch] pad->40
    __shared__ float red[4][800];
    int tid = threadIdx.x, lane = tid & 63, w = tid >> 6;
    int p = lane & 15, g = lane >> 4;
    for (int e = tid; e < 512; e += TPB) w1s[e] = w1[e];
    if (tid < 64) p1[tid] = prm1[tid];
    // W2 fragments: lane (p,g) of block cb holds W2[cb*16+p][g*8..+7] fp16
    f16x8 Wf[4];
#pragma unroll
    for (int cb = 0; cb < 4; ++cb) {
        const float* wr = w2 + (cb * 16 + p) * 32 + g * 8;
        float4 a4 = *(const float4*)wr;
        float4 b4 = *(const float4*)(wr + 4);
        Wf[cb] = (f16x8){ (f16)a4.x, (f16)a4.y, (f16)a4.z, (f16)a4.w,
                          (f16)b4.x, (f16)b4.y, (f16)b4.z, (f16)b4.w };
    }
    __syncthreads();
    unsigned pid = blockIdx.x * TPB + tid;
    const float* xp = x + (size_t)(pid >> 14) * 16 * HWc + (pid & 16383u);
    float xv[16];
#pragma unroll
    for (int c = 0; c < 16; ++c) xv[c] = xp[(size_t)c * HWc];
    f16* vp = V + tid * 40;
#pragma unroll
    for (int c8 = 0; c8 < 4; ++c8) {
        f16x8 hv;
#pragma unroll
        for (int j = 0; j < 8; ++j) {
            int co = c8 * 8 + j;
            float a = 0.f;
#pragma unroll
            for (int c4 = 0; c4 < 4; ++c4) {
                float4 ww = *(const float4*)&w1s[co * 16 + c4 * 4];
                a = fmaf(xv[c4 * 4 + 0], ww.x, a); a = fmaf(xv[c4 * 4 + 1], ww.y, a);
                a = fmaf(xv[c4 * 4 + 2], ww.z, a); a = fmaf(xv[c4 * 4 + 3], ww.w, a);
            }
            hv[j] = (f16)fmaxf(0.f, fmaf(a, p1[co * 2], p1[co * 2 + 1]));
        }
        *(f16x8*)(vp + c8 * 8) = hv;
    }
    __syncthreads();
    // conv2: wave w owns px [w*64, w*64+64)
    unsigned Pb = blockIdx.x * TPB + (unsigned)(w * 64);
#pragma unroll
    for (int f = 0; f < 4; ++f) {
        int pxl = w * 64 + f * 16 + p;
        f16x8 bf = *(const f16x8*)&V[pxl * 40 + g * 8];
        unsigned Pg = Pb + (unsigned)(f * 16 + p);
#pragma unroll
        for (int cb = 0; cb < 4; ++cb) {
            f32x4 d = {0.f, 0.f, 0.f, 0.f};
            d = __builtin_amdgcn_mfma_f32_16x16x32_f16(Wf[cb], bf, d, 0, 0, 0);
            f16x4 o4 = { (f16)d[0], (f16)d[1], (f16)d[2], (f16)d[3] };
            *(f16x4*)(t2r + (size_t)Pg * 64 + cb * 16 + 4 * g) = o4;
        }
    }
    // Gram(v1): 32x32 in 3 blocks (0,0),(0,1),(1,1) + col sums
    const f16 one = (f16)1.0f;
    const f16x8 kOnes = {one, one, one, one, one, one, one, one};
    f32x4 accG[3] = {{0.f,0.f,0.f,0.f},{0.f,0.f,0.f,0.f},{0.f,0.f,0.f,0.f}};
    f32x4 accS[2] = {{0.f,0.f,0.f,0.f},{0.f,0.f,0.f,0.f}};
#pragma unroll
    for (int c2 = 0; c2 < 2; ++c2) {
        int px0 = w * 64 + c2 * 32;
        f16x8 fb[2];
#pragma unroll
        for (int cb2 = 0; cb2 < 2; ++cb2)
#pragma unroll
            for (int j = 0; j < 8; ++j)
                fb[cb2][j] = V[(px0 + g * 8 + j) * 40 + cb2 * 16 + p];
        accG[0] = __builtin_amdgcn_mfma_f32_16x16x32_f16(fb[0], fb[0], accG[0], 0, 0, 0);
        accG[1] = __builtin_amdgcn_mfma_f32_16x16x32_f16(fb[0], fb[1], accG[1], 0, 0, 0);
        accG[2] = __builtin_amdgcn_mfma_f32_16x16x32_f16(fb[1], fb[1], accG[2], 0, 0, 0);
        accS[0] = __builtin_amdgcn_mfma_f32_16x16x32_f16(kOnes, fb[0], accS[0], 0, 0, 0);
        accS[1] = __builtin_amdgcn_mfma_f32_16x16x32_f16(kOnes, fb[1], accS[1], 0, 0, 0);
    }
#pragma unroll
    for (int blk = 0; blk < 3; ++blk)
#pragma unroll
        for (int r = 0; r < 4; ++r)
            red[w][blk * 256 + (4 * g + r) * 16 + p] = accG[blk][r];
    if (g == 0) { red[w][768 + p] = accS[0][0]; red[w][784 + p] = accS[1][0]; }
    __syncthreads();
    for (int e = tid; e < 800; e += TPB) {
        float v = red[0][e] + red[1][e] + red[2][e] + red[3][e];
        atomicAdd(&bkt[(blockIdx.x & 63u) * 800u + (unsigned)e], v);
    }
}

// ---- stats2 finalize: Gram(v1) -> mean/var of conv2 raw (fp16-consistent W2) ----
__global__ void k_sfin2g(const float* __restrict__ bkt, const float* __restrict__ w2,
                         const float* __restrict__ g2, const float* __restrict__ bb2,
                         float* __restrict__ prm) {
    __shared__ float G[768];
    __shared__ float S[32];
    int tid = threadIdx.x;   // 256
    for (int e = tid; e < 768; e += 256) {
        float v = 0.f;
        for (int s = 0; s < 64; ++s) v += bkt[s * 800 + e];
        G[e] = v;
    }
    if (tid < 32) {
        float v = 0.f;
        for (int s = 0; s < 64; ++s) v += bkt[s * 800 + 768 + tid];
        S[tid] = v;
    }
    __syncthreads();
    if (tid < 64) {
        float wv[32];
#pragma unroll
        for (int i = 0; i < 32; ++i) wv[i] = (float)(f16)w2[tid * 32 + i];
        float m = 0.f, e2 = 0.f;
#pragma unroll
        for (int i = 0; i < 32; ++i) {
            m += wv[i] * S[i];
            int bi = i >> 4, il = i & 15;
            float t = 0.f;
#pragma unroll
            for (int j = 0; j < 32; ++j) {
                int bj = j >> 4, jl = j & 15;
                float Gij;
                if (bi <= bj) Gij = G[(bi == 0 ? (bj == 0 ? 0 : 1) : 2) * 256 + il * 16 + jl];
                else          Gij = G[(bj == 0 ? 1 : 2) * 256 + jl * 16 + il];
                t += wv[j] * Gij;
            }
            e2 += wv[i] * t;
        }
        float mean = m * NINV;
        float var = e2 * NINV - mean * mean;
        float sc = g2[tid] * rsqrtf(var + 1e-5f);
        prm[tid * 2] = sc;
        prm[tid * 2 + 1] = bb2[tid] - mean * sc;
    }
}

// ------------- generic stats finalize (sum/sumsq buckets, conv3/conv4) -------------
__global__ void k_sfin(const float* __restrict__ bkt, const float* __restrict__ g,
                       const float* __restrict__ bb, float* __restrict__ prm, int C) {
    int co = threadIdx.x;
    float s = 0.f, q = 0.f;
    for (int k = 0; k < 64; ++k) { s += bkt[(k * C + co) * 2]; q += bkt[(k * C + co) * 2 + 1]; }
    float mean = s * NINV;
    float var = q * NINV - mean * mean;
    float sc = g[co] * rsqrtf(var + 1e-5f);
    prm[co * 2] = sc;
    prm[co * 2 + 1] = bb[co] - mean * sc;
}

// ---- weight prep: OIHW fp32 -> fp16 fragment-lane-ordered, ks-contiguous ----
template <int CI>
__global__ void k_wprep(const float* __restrict__ w, float* __restrict__ wsg) {
    constexpr int KS = CI / 32;
    int t = blockIdx.x * 256 + threadIdx.x;
    if (t >= KS * 18 * 64) return;
    int lane = t & 63, fr = t >> 6;
    int cf = fr & 1, tap = (fr >> 1) % 9, ks = fr / 18;
    int g = lane >> 4, p = lane & 15;
    int co = cf * 16 + p;
    f16x8 hv;
#pragma unroll
    for (int j = 0; j < 8; ++j) {
        int ci = ks * 32 + g * 8 + j;
        hv[j] = (f16)w[(co * CI + ci) * 9 + tap];
    }
    ((f16x8*)wsg)[fr * 64 + lane] = hv;
}

// ------ Pass C/D: 3x3 conv, BN+ReLU fused on LDS staging, MFMA ------
template <int CI>
__global__ __launch_bounds__(512, 4) void k_conv3(const f16* __restrict__ in,
                                                  const float* __restrict__ wsg,
                                                  const float* __restrict__ prm,
                                                  f16* __restrict__ outp,
                                                  float* __restrict__ bkt) {
    constexpr int KS = CI / 32;
    __shared__ __align__(16) struct {
        f16   Wl[18 * 512];      // 18 KB: current ks weight frags
        f16   Al[6 * 128 * 32];  // 48 KB: BN'd A tile (rows y0-1..y0+4)
        float red[8][64];
    } sh;
    int tid = threadIdx.x;
    int lane = tid & 63, w = tid >> 6;
    int p = lane & 15, g = lane >> 4;
    int rw = w >> 1, h = w & 1;
    int cw = tid & 3, pxt = tid >> 2;

    unsigned o = blockIdx.x;
    unsigned xcd = o & 7u, q = o >> 3;
    unsigned rg = q & 31u, grp = q >> 5;
    unsigned b = (grp << 3) | xcd;        // batch pinned to XCD for L2 locality
    int y0 = (int)rg * 4;

    float psc[KS][8], psh[KS][8];
#pragma unroll
    for (int ks = 0; ks < KS; ++ks)
#pragma unroll
        for (int j = 0; j < 8; ++j) {
            int ch = ks * 32 + cw * 8 + j;
            psc[ks][j] = prm[ch * 2];
            psh[ks][j] = prm[ch * 2 + 1];
        }

    bool mask0 = (h == 0 && p == 0);
    bool mask1 = (h == 1 && p == 15);
    const f16x8 kZ = {0, 0, 0, 0, 0, 0, 0, 0};

    f32x4 acc[4][2];
#pragma unroll
    for (int f = 0; f < 4; ++f)
#pragma unroll
        for (int cf = 0; cf < 2; ++cf) acc[f][cf] = (f32x4){0.f, 0.f, 0.f, 0.f};

    for (int ks = 0; ks < KS; ++ks) {
        if (ks) __syncthreads();          // WAR on LDS reuse
        // ---- stage weights (18 KB linear, async) ----
#pragma unroll
        for (int c0 = 0; c0 < 1152; c0 += 512) {
            if (c0 + (w << 6) < 1152) {   // wave-uniform guard
                int c = c0 + tid;
                gl_lds16(wsg + (size_t)(ks * 4608 + c * 4), &sh.Wl[c * 8]);
            }
        }
        // ---- stage A rows, BN+ReLU applied; zero at image border ----
#pragma unroll
        for (int r6 = 0; r6 < 6; ++r6) {
            int yy = y0 - 1 + r6;
            f16* dst = &sh.Al[r6 * 4096 + tid * 8];
            if ((unsigned)yy < 128u) {
                const f16* s = in + ((size_t)(b * 128u + (unsigned)yy) * 128u + pxt) * CI
                                  + ks * 32 + cw * 8;
                f16x8 raw = *(const f16x8*)s;
                f16x8 o8;
#pragma unroll
                for (int j = 0; j < 8; ++j)
                    o8[j] = (f16)fmaxf(0.f, fmaf((float)raw[j], psc[ks][j], psh[ks][j]));
                *(f16x8*)dst = o8;
            } else {
                *(f16x8*)dst = kZ;
            }
        }
        __syncthreads();
        // ---- 9 taps x 4 px-frags x 2 co-halves ----
        const f16x8* Wv = (const f16x8*)sh.Wl;
        for (int dyi = 0; dyi < 3; ++dyi) {
            int ar = rw + dyi;
#pragma unroll
            for (int dxi = 0; dxi < 3; ++dxi) {
                int tap = dyi * 3 + dxi;
                f16x8 b0 = Wv[(tap * 2 + 0) * 64 + lane];
                f16x8 b1 = Wv[(tap * 2 + 1) * 64 + lane];
#pragma unroll
                for (int f = 0; f < 4; ++f) {
                    int px = h * 64 + f * 16 + p + dxi - 1;
                    f16x8 a = *(const f16x8*)&sh.Al[(ar * 128 + px) * 32 + g * 8];
                    if (dxi == 0 && f == 0) { if (mask0) a = kZ; }
                    if (dxi == 2 && f == 3) { if (mask1) a = kZ; }
                    acc[f][0] = __builtin_amdgcn_mfma_f32_16x16x32_f16(b0, a, acc[f][0], 0, 0, 0);
                    acc[f][1] = __builtin_amdgcn_mfma_f32_16x16x32_f16(b1, a, acc[f][1], 0, 0, 0);
                }
            }
        }
    }

    // ---- stats: lane(p,g) reg r of half cf holds co = cf*16+g*4+r ----
    float sv[8], qv[8];
#pragma unroll
    for (int cf = 0; cf < 2; ++cf)
#pragma unroll
        for (int r = 0; r < 4; ++r) {
            float s = acc[0][cf][r] + acc[1][cf][r] + acc[2][cf][r] + acc[3][cf][r];
            float qq = acc[0][cf][r] * acc[0][cf][r] + acc[1][cf][r] * acc[1][cf][r] +
                       acc[2][cf][r] * acc[2][cf][r] + acc[3][cf][r] * acc[3][cf][r];
#pragma unroll
            for (int m = 1; m < 16; m <<= 1) {
                s += __shfl_xor(s, m, 64);
                qq += __shfl_xor(qq, m, 64);
            }
            sv[cf * 4 + r] = s; qv[cf * 4 + r] = qq;
        }
    if (p == 0) {
#pragma unroll
        for (int cf = 0; cf < 2; ++cf)
#pragma unroll
            for (int r = 0; r < 4; ++r) {
                int co = cf * 16 + g * 4 + r;
                sh.red[w][co * 2] = sv[cf * 4 + r];
                sh.red[w][co * 2 + 1] = qv[cf * 4 + r];
            }
    }

    // ---- store raw fp16 NHWC: lane packs 4 consecutive co -> 8B stores ----
    unsigned pxb = b * 16384u + (unsigned)((y0 + rw) * 128 + h * 64 + p);
#pragma unroll
    for (int f = 0; f < 4; ++f)
#pragma unroll
        for (int cf = 0; cf < 2; ++cf) {
            f16x4 o4 = { (f16)acc[f][cf][0], (f16)acc[f][cf][1],
                         (f16)acc[f][cf][2], (f16)acc[f][cf][3] };
            *(f16x4*)(outp + (size_t)(pxb + f * 16u) * 32u + (unsigned)(cf * 16 + g * 4)) = o4;
        }

    __syncthreads();
    if (tid < 64) {
        float v = 0.f;
#pragma unroll
        for (int ww = 0; ww < 8; ++ww) v += sh.red[ww][tid];
        atomicAdd(&bkt[(o & 63u) * 64u + (unsigned)tid], v);
    }
}

// ---- Pass E: BN4+ReLU + fc1/tanh + fc2/tanh via MFMA (SPLIT hi/lo weights) ----
// Weight fp16 quantization is systematic (does not average over tokens) and
// flipped the argsort in r5; split A-operand restores fp32-class weights.
__global__ __launch_bounds__(TPB) void k_fcm(const f16* __restrict__ t4,
                                             const float* __restrict__ prm4,
                                             const float* __restrict__ fw1,
                                             const float* __restrict__ fb1,
                                             const float* __restrict__ fw2,
                                             const float* __restrict__ fb2,
                                             float* __restrict__ y0sum) {
    __shared__ __align__(16) struct {
        f16   V1[256 * 40];    // BN'd tokens [px][32ch] pad->40
        f16   V2[256 * 40];    // h1 (tanh'd fc1) same layout
        float p4[64], b1s[32], b2s[16];
        float red[4][16];
    } sh;
    int tid = threadIdx.x, lane = tid & 63, w = tid >> 6;
    int p = lane & 15, g = lane >> 4;
    if (tid < 64) sh.p4[tid] = prm4[tid];
    if (tid < 32) sh.b1s[tid] = fb1[tid];
    if (tid < 16) sh.b2s[tid] = fb2[tid];
    // W frags hi/lo: lane (p,g) of half cb holds W[cb*16+p][g*8..+7]
    f16x8 W1h[2], W1l[2], W2h, W2l;
#pragma unroll
    for (int cb = 0; cb < 2; ++cb) {
        const float* wr = fw1 + (cb * 16 + p) * 32 + g * 8;
#pragma unroll
        for (int j = 0; j < 8; ++j) {
            float v = wr[j];
            f16 hh = (f16)v;
            W1h[cb][j] = hh;
            W1l[cb][j] = (f16)(v - (float)hh);
        }
    }
    {
        const float* wr = fw2 + p * 32 + g * 8;
#pragma unroll
        for (int j = 0; j < 8; ++j) {
            float v = wr[j];
            f16 hh = (f16)v;
            W2h[j] = hh;
            W2l[j] = (f16)(v - (float)hh);
        }
    }
    __syncthreads();
    // ---- stage BN4+ReLU tokens ----
    unsigned pid = blockIdx.x * TPB + tid;
    const f16x8* tv = (const f16x8*)(t4 + (size_t)pid * 32);
    f16* vp = sh.V1 + tid * 40;
#pragma unroll
    for (int c8 = 0; c8 < 4; ++c8) {
        f16x8 raw = tv[c8];
        f16x8 o8;
#pragma unroll
        for (int j = 0; j < 8; ++j) {
            int c = c8 * 8 + j;
            o8[j] = (f16)fmaxf(0.f, fmaf((float)raw[j], sh.p4[c * 2], sh.p4[c * 2 + 1]));
        }
        *(f16x8*)(vp + c8 * 8) = o8;
    }
    __syncthreads();
    // ---- fc1 via split MFMA: wave w owns px [w*64, w*64+64) ----
    float bb1[8];
#pragma unroll
    for (int cb = 0; cb < 2; ++cb)
#pragma unroll
        for (int r = 0; r < 4; ++r) bb1[cb * 4 + r] = sh.b1s[cb * 16 + g * 4 + r];
#pragma unroll
    for (int f = 0; f < 4; ++f) {
        int pxl = w * 64 + f * 16 + p;
        f16x8 bf = *(const f16x8*)&sh.V1[pxl * 40 + g * 8];
#pragma unroll
        for (int cb = 0; cb < 2; ++cb) {
            f32x4 d = {0.f, 0.f, 0.f, 0.f};
            d = __builtin_amdgcn_mfma_f32_16x16x32_f16(W1l[cb], bf, d, 0, 0, 0);
            d = __builtin_amdgcn_mfma_f32_16x16x32_f16(W1h[cb], bf, d, 0, 0, 0);
            f16x4 h4;
#pragma unroll
            for (int r = 0; r < 4; ++r) h4[r] = (f16)tanh_fast(d[r] + bb1[cb * 4 + r]);
            *(f16x4*)&sh.V2[pxl * 40 + cb * 16 + g * 4] = h4;
        }
    }
    __syncthreads();
    // ---- fc2 via split MFMA + tanh + sum over tokens ----
    float bb2[4];
#pragma unroll
    for (int r = 0; r < 4; ++r) bb2[r] = sh.b2s[g * 4 + r];
    float s4[4] = {0.f, 0.f, 0.f, 0.f};
#pragma unroll
    for (int f = 0; f < 4; ++f) {
        int pxl = w * 64 + f * 16 + p;
        f16x8 bf = *(const f16x8*)&sh.V2[pxl * 40 + g * 8];
        f32x4 d = {0.f, 0.f, 0.f, 0.f};
        d = __builtin_amdgcn_mfma_f32_16x16x32_f16(W2l, bf, d, 0, 0, 0);
        d = __builtin_amdgcn_mfma_f32_16x16x32_f16(W2h, bf, d, 0, 0, 0);
#pragma unroll
        for (int r = 0; r < 4; ++r) s4[r] += tanh_fast(d[r] + bb2[r]);
    }
#pragma unroll
    for (int r = 0; r < 4; ++r) {
#pragma unroll
        for (int m = 1; m < 16; m <<= 1) s4[r] += __shfl_xor(s4[r], m, 64);
    }
    if (p == 0) {
#pragma unroll
        for (int r = 0; r < 4; ++r) sh.red[w][g * 4 + r] = s4[r];
    }
    __syncthreads();
    if (tid < 16) {
        float s = sh.red[0][tid] + sh.red[1][tid] + sh.red[2][tid] + sh.red[3][tid];
        atomicAdd(&y0sum[(blockIdx.x >> 6) * 16u + tid], s);
    }
}

// -------- finalize y0 -> wn, stable argsort, vals/order/wi, Cm, idx --------
__global__ void k_final(const float* __restrict__ y0sum, float* __restrict__ out,
                        float* __restrict__ Cm, int* __restrict__ idxb) {
    int b = threadIdx.x; // 64 threads
    float y0[16]; float nrm = 0.f;
#pragma unroll
    for (int i = 0; i < 16; ++i) { y0[i] = y0sum[b * 16 + i] * (1.0f / 16384.0f); nrm += y0[i] * y0[i]; }
    nrm = sqrtf(nrm);
    float wn[16]; int id[16];
#pragma unroll
    for (int i = 0; i < 16; ++i) { wn[i] = fabsf(y0[i]) * nrm; id[i] = i; }
    for (int i = 1; i < 16; ++i) {
        float k = wn[i]; int ii = id[i]; int j = i - 1;
        while (j >= 0 && wn[j] < k) { wn[j + 1] = wn[j]; id[j + 1] = id[j]; --j; }
        wn[j + 1] = k; id[j + 1] = ii;
    }
    for (int i = 0; i < 16; ++i) {
        out[VALS_OFF + b * 16 + i] = wn[i];
        out[ORDER_OFF + b * 16 + i] = (float)id[i];
    }
    for (int g = 0; g < 5; ++g)
        out[WI_OFF + g * 64 + b] = (wn[g * 3] + wn[g * 3 + 1] + wn[g * 3 + 2]) * (1.0f / 3.0f);
    for (int i = 0; i < 16; ++i)
        for (int j = 0; j < 16; ++j) Cm[b * 256 + i * 16 + j] = y0[i] * y0[j];
    for (int s = 0; s < 15; ++s) idxb[b * 15 + s] = id[s];
}

// -------- read x once -> cgh (Cm @ x) and fi (channel gather) --------
__global__ __launch_bounds__(TPB) void k_out(const float* __restrict__ x,
                                             const float* __restrict__ Cm,
                                             const int* __restrict__ idxb,
                                             float* __restrict__ out) {
    __shared__ float cm[256];
    __shared__ int idl[15];
    int tid = threadIdx.x;
    unsigned b = blockIdx.x >> 6;
    unsigned p = ((blockIdx.x & 63u) << 8) + tid;
    cm[tid] = Cm[b * 256u + tid];
    if (tid < 15) idl[tid] = idxb[b * 15u + tid];
    __syncthreads();
    const float* xp = x + (size_t)b * 16 * HWc + p;
    float xv[16];
#pragma unroll
    for (int j = 0; j < 16; ++j) xv[j] = xp[(size_t)j * HWc];
    float* og = out + CGH_OFF + (size_t)b * 16 * HWc + p;
    for (int i = 0; i < 16; ++i) {
        float a = 0.f;
#pragma unroll
        for (int j = 0; j < 16; ++j) a = fmaf(cm[i * 16 + j], xv[j], a);
        og[(size_t)i * HWc] = a;
    }
#pragma unroll
    for (int s = 0; s < 15; ++s) {
        int ch = idl[s];
        float vv = xp[(size_t)ch * HWc];
        int g = s / 3, r = s - 3 * g;
        out[(size_t)((g * 64 + (int)b) * 3 + r) * HWc + p] = vv;
    }
}

extern "C" void kernel_launch(void* const* d_in, const int* in_sizes, int n_in,
                              void* d_out, int out_size, void* d_ws, size_t ws_size,
                              hipStream_t stream) {
    const float* x    = (const float*)d_in[0];
    const float* w1   = (const float*)d_in[1];
    const float* bn1g = (const float*)d_in[2];  const float* bn1b = (const float*)d_in[3];
    const float* w2   = (const float*)d_in[4];
    const float* bn2g = (const float*)d_in[5];  const float* bn2b = (const float*)d_in[6];
    const float* w3   = (const float*)d_in[7];
    const float* bn3g = (const float*)d_in[8];  const float* bn3b = (const float*)d_in[9];
    const float* w4   = (const float*)d_in[10];
    const float* bn4g = (const float*)d_in[11]; const float* bn4b = (const float*)d_in[12];
    const float* fw1  = (const float*)d_in[13]; const float* fb1  = (const float*)d_in[14];
    const float* fw2  = (const float*)d_in[15]; const float* fb2  = (const float*)d_in[16];
    float* out = (float*)d_out;
    float* wsf = (float*)d_ws;

    // ws layout (float offsets):
    //   t2r @ 0           (33,554,432) : conv2 raw fp16 NHWC [px][64]
    //   t3r @ 33,554,432  (16,777,216) : conv3 raw fp16 NHWC [px][32]
    //   t4h @ 50,331,648  (16,777,216) : conv4 raw fp16 NHWC [px][32]
    //   acc @ 67,108,864  : buckets / params / Cm / idx / weight frags
    f16*   t2r = (f16*)wsf;
    f16*   t3r = (f16*)(wsf + 33554432);
    f16*   t4h = (f16*)(wsf + 50331648);
    float* acc = wsf + 67108864;
    float* b1g = acc;                 // 64*272 = 17408
    float* b2g = acc + 17408;         // 64*800 = 51200
    float* b3  = acc + 68608;         // 8192
    float* b4  = acc + 76800;         // 8192
    float* y0s = acc + 84992;         // 1024   (zeroed range ends at 86016)
    float* pr1 = acc + 86016;  float* pr2 = acc + 86080;
    float* pr3 = acc + 86208;  float* pr4 = acc + 86272;
    float* Cm  = acc + 86336;         // 16384
    int*   idxb = (int*)(acc + 102720); // 960
    float* wsg3 = acc + 103680;       // 9216 floats (36 frags)
    float* wsg4 = acc + 112896;       // 4608 floats (18 frags)
    size_t need = (size_t)(67108864 + 117504) * 4;
    if (ws_size < need) return;

    hipMemsetAsync(acc, 0, 86016 * 4, stream);  // zero all stat buckets + y0sum

    k_wprep<64><<<9, 256, 0, stream>>>(w3, wsg3);
    k_wprep<32><<<5, 256, 0, stream>>>(w4, wsg4);
    k_gramx<<<512, TPB, 0, stream>>>(x, b1g);
    k_sfin1g<<<1, 256, 0, stream>>>(b1g, w1, bn1g, bn1b, pr1);
    k_conv2m<<<4096, TPB, 0, stream>>>(x, w1, w2, pr1, t2r, b2g);
    k_sfin2g<<<1, 256, 0, stream>>>(b2g, w2, bn2g, bn2b, pr2);
    k_conv3<64><<<2048, 512, 0, stream>>>(t2r, wsg3, pr2, t3r, b3);
    k_sfin<<<1, 32, 0, stream>>>(b3, bn3g, bn3b, pr3, 32);
    k_conv3<32><<<2048, 512, 0, stream>>>(t3r, wsg4, pr3, t4h, b4);
    k_sfin<<<1, 32, 0, stream>>>(b4, bn4g, bn4b, pr4, 32);
    k_fcm<<<4096, TPB, 0, stream>>>(t4h, pr4, fw1, fb1, fw2, fb2, y0s);
    k_final<<<1, 64, 0, stream>>>(y0s, out, Cm, idxb);
    k_out<<<4096, TPB, 0, stream>>>(x, Cm, idxb, out);
}